// Round 12
// baseline (318.660 us; speedup 1.0000x reference)
//
#include <hip/hip_runtime.h>

#define NTOK 4096
#define CHAN 512
#define GSIZE 65536
#define RSQRT2 0.7071067811865476f
#define QSCALE 0.2550316360552602f   // (1/sqrt(32)) * log2(e)  -> exp2 domain
#define WS_NEEDED ((size_t)(16384 + 8 * 1024 * 1024))

typedef unsigned short ushort_t;
typedef __attribute__((ext_vector_type(8))) short bf16x8;
typedef __attribute__((ext_vector_type(4))) float f32x4;

__device__ __forceinline__ ushort_t f2b(float f) {
    unsigned u = __float_as_uint(f);
    unsigned r = (u + 0x7FFFu + ((u >> 16) & 1u)) >> 16;
    return (ushort_t)r;
}
__device__ __forceinline__ unsigned pack2r(float a, float b) {
    unsigned ua = __float_as_uint(a), ub = __float_as_uint(b);
    return ((ua + 0x8000u) >> 16) | ((ub + 0x8000u) & 0xFFFF0000u);
}
__device__ __forceinline__ bf16x8 ldfrag(const ushort_t* p) {
    return __builtin_bit_cast(bf16x8, *(const uint4*)p);
}

__global__ void diag_kernel(float* out, float v) {
    if (threadIdx.x == 0 && blockIdx.x == 0) out[0] = v;
}

// ---- Fused GroupNorm: per-channel affine coeffs for qn and vn (one x pass).
__global__ __launch_bounds__(256) void gn_all(const float* __restrict__ x,
                                              const float* __restrict__ gnw,
                                              const float* __restrict__ gnb,
                                              float* __restrict__ qa,
                                              float* __restrict__ qd,
                                              float* __restrict__ va,
                                              float* __restrict__ vd) {
    int g = blockIdx.x, t = threadIdx.x;
    int cl = t >> 4, sl = t & 15;
    const float4* p = (const float4*)(x + (size_t)g * GSIZE + (size_t)cl * 4096);
    float s = 0.f, ss = 0.f;
    for (int i = 0; i < 64; i++) {
        float4 f = p[i * 16 + sl];
        s += f.x + f.y + f.z + f.w;
        ss += f.x * f.x + f.y * f.y + f.z * f.z + f.w * f.w;
    }
    #pragma unroll
    for (int off = 8; off > 0; off >>= 1) {
        s += __shfl_xor(s, off);
        ss += __shfl_xor(ss, off);
    }
    __shared__ float Sc[16], SSc[16];
    if (sl == 0) { Sc[cl] = s; SSc[cl] = ss; }
    __syncthreads();
    if (t < 16) {
        float S = Sc[t], SS = SSc[t];
        float gs = S, gss = SS;
        #pragma unroll
        for (int off = 8; off > 0; off >>= 1) {
            gs += __shfl_xor(gs, off);
            gss += __shfl_xor(gss, off);
        }
        float mu = gs * (1.f / GSIZE);
        float var = gss * (1.f / GSIZE) - mu * mu;
        float r1 = rsqrtf(var + 1e-6f);
        int c = g * 16 + t;
        float wc = gnw[c], bc = gnb[c];
        float a1 = r1 * wc;
        float d1 = bc - mu * a1;
        qa[c] = a1; qd[c] = d1;
        float S2 = a1 * S + 4096.f * d1;
        float SS2 = a1 * a1 * SS + 2.f * a1 * d1 * S + 4096.f * d1 * d1;
        float gs2 = S2, gss2 = SS2;
        #pragma unroll
        for (int off = 8; off > 0; off >>= 1) {
            gs2 += __shfl_xor(gs2, off);
            gss2 += __shfl_xor(gss2, off);
        }
        float mu2 = gs2 * (1.f / GSIZE);
        float var2 = gss2 * (1.f / GSIZE) - mu2 * mu2;
        float r2 = rsqrtf(var2 + 1e-6f);
        float a2 = r2 * wc;
        va[c] = a1 * a2;
        vd[c] = a2 * (d1 - mu2) + bc;
    }
}

// ---- Fold GN offsets into biases: b'[o] = b[o] + sum_c W[o][c]*d[c].
// blockIdx.x: 0 -> (wq,qd,bq), 1 -> (wk,vd,bk), 2 -> (wv,vd,bv).
__global__ __launch_bounds__(256) void bias_fold(const float* __restrict__ wq,
                                                 const float* __restrict__ wk,
                                                 const float* __restrict__ wv,
                                                 const float* __restrict__ bq,
                                                 const float* __restrict__ bk,
                                                 const float* __restrict__ bv,
                                                 const float* __restrict__ qd,
                                                 const float* __restrict__ vd,
                                                 float* __restrict__ bqf,
                                                 float* __restrict__ bkf,
                                                 float* __restrict__ bvf) {
    int m = blockIdx.x, t = threadIdx.x;
    const float* W = (m == 0) ? wq : (m == 1) ? wk : wv;
    const float* b = (m == 0) ? bq : (m == 1) ? bk : bv;
    const float* d = (m == 0) ? qd : vd;
    float* outp    = (m == 0) ? bqf : (m == 1) ? bkf : bvf;
    #pragma unroll
    for (int rep = 0; rep < 2; rep++) {
        int o = rep * 256 + t;
        const float4* wr = (const float4*)(W + (size_t)o * 512);
        const float4* dr = (const float4*)d;
        float acc = 0.f;
        for (int i = 0; i < 128; i++) {
            float4 wv4 = wr[i], dv4 = dr[i];
            acc += wv4.x * dv4.x + wv4.y * dv4.y + wv4.z * dv4.z + wv4.w * dv4.w;
        }
        outp[o] = b[o] + acc;
    }
}

// ---- XT = bf16(x)^T : [4096 tok][512 chan], token-major (GEMM B operand).
__global__ __launch_bounds__(256) void xt_prep(const float* __restrict__ x,
                                               ushort_t* __restrict__ XT) {
    __shared__ float Tl[64][65];
    int t = threadIdx.x;
    int tbase = blockIdx.x << 6, cbase = blockIdx.y << 6;
    int cl = t >> 2, tq = t & 3;
    #pragma unroll
    for (int i = 0; i < 4; i++) {
        float4 f = *(const float4*)&x[(size_t)(cbase + cl) * NTOK + tbase + tq * 16 + i * 4];
        Tl[cl][tq * 16 + i * 4 + 0] = f.x;
        Tl[cl][tq * 16 + i * 4 + 1] = f.y;
        Tl[cl][tq * 16 + i * 4 + 2] = f.z;
        Tl[cl][tq * 16 + i * 4 + 3] = f.w;
    }
    __syncthreads();
    #pragma unroll
    for (int i = 0; i < 2; i++) {
        int idx = 2 * t + i;
        int row = idx >> 3, c8 = idx & 7;
        float v[8];
        #pragma unroll
        for (int j = 0; j < 8; j++) v[j] = Tl[c8 * 8 + j][row];
        uint4 u;
        u.x = pack2r(v[0], v[1]);
        u.y = pack2r(v[2], v[3]);
        u.z = pack2r(v[4], v[5]);
        u.w = pack2r(v[6], v[7]);
        *(uint4*)&XT[(size_t)(tbase + row) * 512 + cbase + c8 * 8] = u;
    }
}

// ---- QKV projection. M=1536 (q|k|v), tile 128m x 128n, K-step 32.
// A = W row-tile, fp32 -> (w*aff) -> bf16 staged in LDS. B = XT direct frags.
// Q -> QT token-major (scaled QSCALE); K -> KT token-major; V -> [chan][tok].
__global__ __launch_bounds__(256) void qkv_mfma(const ushort_t* __restrict__ XT,
                                                const float* __restrict__ wq,
                                                const float* __restrict__ wk,
                                                const float* __restrict__ wv,
                                                const float* __restrict__ bqf,
                                                const float* __restrict__ bkf,
                                                const float* __restrict__ bvf,
                                                const float* __restrict__ qa,
                                                const float* __restrict__ va,
                                                ushort_t* __restrict__ QT,
                                                ushort_t* __restrict__ KT,
                                                ushort_t* __restrict__ Vb) {
    __shared__ __align__(16) ushort_t Wl[128][40];
    __shared__ __align__(16) ushort_t Tl[128][72];
    int t = threadIdx.x;
    int nbase = blockIdx.x << 7;
    int y = blockIdx.y;
    int buf = y >> 2;
    int obase = (y & 3) << 7;
    const float* W    = (buf == 0) ? wq : (buf == 1) ? wk : wv;
    const float* bias = (buf == 0) ? bqf : (buf == 1) ? bkf : bvf;
    const float* aff  = (buf == 0) ? qa : va;

    int w = t >> 6, lane = t & 63, q15 = lane & 15, quad = lane >> 4;
    f32x4 acc[2][8];
    #pragma unroll
    for (int i = 0; i < 2; i++)
        #pragma unroll
        for (int j = 0; j < 8; j++) acc[i][j] = (f32x4){0.f, 0.f, 0.f, 0.f};

    int ml = t & 127, kg = t >> 7;
    for (int ck = 0; ck < 512; ck += 32) {
        __syncthreads();
        {   // A: 128 rows x 32 k, fold affine, fp32->bf16
            const float* src = W + (size_t)(obase + ml) * 512 + ck + kg * 16;
            const float* ap = aff + ck + kg * 16;
            float v[16];
            #pragma unroll
            for (int i = 0; i < 4; i++) {
                float4 f = *(const float4*)(src + i * 4);
                v[i * 4 + 0] = f.x * ap[i * 4 + 0];
                v[i * 4 + 1] = f.y * ap[i * 4 + 1];
                v[i * 4 + 2] = f.z * ap[i * 4 + 2];
                v[i * 4 + 3] = f.w * ap[i * 4 + 3];
            }
            uint4 u0, u1;
            u0.x = pack2r(v[0], v[1]);   u0.y = pack2r(v[2], v[3]);
            u0.z = pack2r(v[4], v[5]);   u0.w = pack2r(v[6], v[7]);
            u1.x = pack2r(v[8], v[9]);   u1.y = pack2r(v[10], v[11]);
            u1.z = pack2r(v[12], v[13]); u1.w = pack2r(v[14], v[15]);
            *(uint4*)&Wl[ml][kg * 16] = u0;
            *(uint4*)&Wl[ml][kg * 16 + 8] = u1;
        }
        __syncthreads();
        bf16x8 af0 = ldfrag(&Wl[w * 32 + q15][quad * 8]);
        bf16x8 af1 = ldfrag(&Wl[w * 32 + 16 + q15][quad * 8]);
        #pragma unroll
        for (int n8 = 0; n8 < 8; n8++) {
            bf16x8 bfv = ldfrag(&XT[(size_t)(nbase + n8 * 16 + q15) * 512 + ck + quad * 8]);
            acc[0][n8] = __builtin_amdgcn_mfma_f32_16x16x32_bf16(af0, bfv, acc[0][n8], 0, 0, 0);
            acc[1][n8] = __builtin_amdgcn_mfma_f32_16x16x32_bf16(af1, bfv, acc[1][n8], 0, 0, 0);
        }
    }

    if (buf == 2) {   // V: [chan][tok]
        #pragma unroll
        for (int mi = 0; mi < 2; mi++)
            #pragma unroll
            for (int r = 0; r < 4; r++) {
                int o = obase + w * 32 + mi * 16 + quad * 4 + r;
                float bo = bias[o];
                #pragma unroll
                for (int n8 = 0; n8 < 8; n8++)
                    Vb[(size_t)o * NTOK + nbase + n8 * 16 + q15] = f2b(acc[mi][n8][r] + bo);
            }
        return;
    }

    ushort_t* dstT = (buf == 0) ? QT : KT;
    float qs = (buf == 0) ? QSCALE : 1.0f;
    for (int half = 0; half < 2; half++) {
        __syncthreads();
        if ((w >> 1) == half) {
            int wl = w & 1;
            #pragma unroll
            for (int mi = 0; mi < 2; mi++)
                #pragma unroll
                for (int r = 0; r < 4; r++) {
                    int mt = w * 32 + mi * 16 + quad * 4 + r;
                    int mloc = wl * 32 + mi * 16 + quad * 4 + r;
                    float bo = bias[obase + mt];
                    #pragma unroll
                    for (int n8 = 0; n8 < 8; n8++)
                        Tl[n8 * 16 + q15][mloc] = f2b((acc[mi][n8][r] + bo) * qs);
                }
        }
        __syncthreads();
        #pragma unroll
        for (int b = 0; b < 4; b++) {
            int j = b * 256 + t;
            int row = j >> 3, ch = j & 7;
            uint4 u = *(const uint4*)&Tl[row][ch * 8];
            *(uint4*)&dstT[(size_t)(nbase + row) * 512 + obase + half * 64 + ch * 8] = u;
        }
    }
}

// ---- Attention v3: LDS-staged K/V shared by 4 waves, 32 q per wave,
// 128-key tiles, exp2-domain softmax (no running max), O overwrites QT rows.
__global__ __launch_bounds__(256) void attn_v3(ushort_t* __restrict__ QT,
                                               const ushort_t* __restrict__ KT,
                                               const ushort_t* __restrict__ V) {
    __shared__ __align__(16) ushort_t Kt[128][40];    // [key][32 chans]
    __shared__ __align__(16) ushort_t Vt[32][136];    // [d][128 keys]
    __shared__ __align__(16) unsigned Plu[4][32][68]; // per-wave [q][key-pairs]
    int h = blockIdx.y;
    int t = threadIdx.x;
    int w = t >> 6, lane = t & 63, q15 = lane & 15, quad = lane >> 4;
    int qbase = (blockIdx.x << 7) + w * 32;
    int hc = h * 32;
    const ushort_t* Vh = V + (size_t)hc * NTOK;

    bf16x8 qf[2];
    #pragma unroll
    for (int qi = 0; qi < 2; qi++)
        qf[qi] = ldfrag(&QT[(size_t)(qbase + qi * 16 + q15) * 512 + hc + quad * 8]);

    f32x4 o[2][2];
    #pragma unroll
    for (int qi = 0; qi < 2; qi++)
        #pragma unroll
        for (int dc = 0; dc < 2; dc++) o[qi][dc] = (f32x4){0.f, 0.f, 0.f, 0.f};
    float l0 = 0.f, l1 = 0.f;

    for (int j0 = 0; j0 < NTOK; j0 += 128) {
        __syncthreads();
        #pragma unroll
        for (int i = 0; i < 2; i++) {     // K stage: 512 uint4
            int idx = 2 * t + i;
            int row = idx >> 2, c = idx & 3;
            *(uint4*)&Kt[row][c * 8] =
                *(const uint4*)&KT[(size_t)(j0 + row) * 512 + hc + c * 8];
        }
        #pragma unroll
        for (int i = 0; i < 2; i++) {     // V stage: 512 uint4
            int idx = 2 * t + i;
            int row = idx >> 4, c = idx & 15;
            *(uint4*)&Vt[row][c * 8] =
                *(const uint4*)&Vh[(size_t)row * NTOK + j0 + c * 8];
        }
        __syncthreads();

        f32x4 st[8][2];
        #pragma unroll
        for (int kt = 0; kt < 8; kt++) {
            bf16x8 kf = ldfrag(&Kt[kt * 16 + q15][quad * 8]);
            #pragma unroll
            for (int qi = 0; qi < 2; qi++) {
                f32x4 z = {0.f, 0.f, 0.f, 0.f};
                st[kt][qi] = __builtin_amdgcn_mfma_f32_16x16x32_bf16(kf, qf[qi], z, 0, 0, 0);
            }
        }

        #pragma unroll
        for (int kt = 0; kt < 8; kt++)
            #pragma unroll
            for (int r = 0; r < 4; r++) {
                float e0 = exp2f(st[kt][0][r]);
                float e1 = exp2f(st[kt][1][r]);
                st[kt][0][r] = e0; l0 += e0;
                st[kt][1][r] = e1; l1 += e1;
            }

        asm volatile("" ::: "memory");
        #pragma unroll
        for (int kt = 0; kt < 8; kt++)
            #pragma unroll
            for (int qi = 0; qi < 2; qi++) {
                uint2 pp;
                pp.x = pack2r(st[kt][qi][0], st[kt][qi][1]);
                pp.y = pack2r(st[kt][qi][2], st[kt][qi][3]);
                *(uint2*)&Plu[w][qi * 16 + q15][kt * 8 + quad * 2] = pp;
            }
        asm volatile("" ::: "memory");

        #pragma unroll
        for (int kc = 0; kc < 4; kc++) {
            bf16x8 vf0 = ldfrag(&Vt[q15][kc * 32 + quad * 8]);
            bf16x8 vf1 = ldfrag(&Vt[16 + q15][kc * 32 + quad * 8]);
            #pragma unroll
            for (int qi = 0; qi < 2; qi++) {
                uint4 pu = *(const uint4*)&Plu[w][qi * 16 + q15][kc * 16 + quad * 4];
                bf16x8 pf = __builtin_bit_cast(bf16x8, pu);
                o[qi][0] = __builtin_amdgcn_mfma_f32_16x16x32_bf16(pf, vf0, o[qi][0], 0, 0, 0);
                o[qi][1] = __builtin_amdgcn_mfma_f32_16x16x32_bf16(pf, vf1, o[qi][1], 0, 0, 0);
            }
        }
    }

    l0 += __shfl_xor(l0, 16); l0 += __shfl_xor(l0, 32);
    l1 += __shfl_xor(l1, 16); l1 += __shfl_xor(l1, 32);
    float li0 = 1.f / l0, li1 = 1.f / l1;

    #pragma unroll
    for (int r = 0; r < 4; r++) {
        int q = quad * 4 + r;
        float lr0 = __shfl(li0, q);
        float lr1 = __shfl(li1, q);
        #pragma unroll
        for (int dc = 0; dc < 2; dc++) {
            QT[(size_t)(qbase + q) * 512 + hc + dc * 16 + q15]      = f2b(o[0][dc][r] * lr0);
            QT[(size_t)(qbase + 16 + q) * 512 + hc + dc * 16 + q15] = f2b(o[1][dc][r] * lr1);
        }
    }
}

// ---- Output projection: A = wo fp32->bf16 staged; B = OT(=QT) direct frags.
__global__ __launch_bounds__(256) void oproj_mfma(const ushort_t* __restrict__ OT,
                                                  const float* __restrict__ wo,
                                                  const float* __restrict__ bo,
                                                  const float* __restrict__ x,
                                                  float* __restrict__ out) {
    __shared__ __align__(16) ushort_t Wl[64][40];
    int t = threadIdx.x;
    int nbase = blockIdx.x << 7;
    int obase = blockIdx.y << 6;
    int w = t >> 6, lane = t & 63, q15 = lane & 15, quad = lane >> 4;

    f32x4 acc[8];
    #pragma unroll
    for (int i = 0; i < 8; i++) acc[i] = (f32x4){0.f, 0.f, 0.f, 0.f};

    int ml = t & 63, kg = t >> 6;
    for (int ck = 0; ck < 512; ck += 32) {
        __syncthreads();
        {
            const float* src = wo + (size_t)(obase + ml) * 512 + ck + kg * 8;
            float4 f0 = *(const float4*)(src + 0);
            float4 f1 = *(const float4*)(src + 4);
            uint4 u;
            u.x = pack2r(f0.x, f0.y); u.y = pack2r(f0.z, f0.w);
            u.z = pack2r(f1.x, f1.y); u.w = pack2r(f1.z, f1.w);
            *(uint4*)&Wl[ml][kg * 8] = u;
        }
        __syncthreads();
        bf16x8 af = ldfrag(&Wl[w * 16 + q15][quad * 8]);
        #pragma unroll
        for (int n8 = 0; n8 < 8; n8++) {
            bf16x8 bfv = ldfrag(&OT[(size_t)(nbase + n8 * 16 + q15) * 512 + ck + quad * 8]);
            acc[n8] = __builtin_amdgcn_mfma_f32_16x16x32_bf16(af, bfv, acc[n8], 0, 0, 0);
        }
    }

    #pragma unroll
    for (int r = 0; r < 4; r++) {
        int o = obase + w * 16 + quad * 4 + r;
        float b = bo[o];
        #pragma unroll
        for (int n8 = 0; n8 < 8; n8++) {
            size_t idx = (size_t)o * NTOK + nbase + n8 * 16 + q15;
            out[idx] = (acc[n8][r] + b + x[idx]) * RSQRT2;
        }
    }
}

extern "C" void kernel_launch(void* const* d_in, const int* in_sizes, int n_in,
                              void* d_out, int out_size, void* d_ws, size_t ws_size,
                              hipStream_t stream) {
    const float* x   = (const float*)d_in[0];
    const float* gnw = (const float*)d_in[1];
    const float* gnb = (const float*)d_in[2];
    const float* wq  = (const float*)d_in[3];
    const float* bq  = (const float*)d_in[4];
    const float* wk  = (const float*)d_in[5];
    const float* bk  = (const float*)d_in[6];
    const float* wv  = (const float*)d_in[7];
    const float* bv  = (const float*)d_in[8];
    const float* wo  = (const float*)d_in[9];
    const float* bo  = (const float*)d_in[10];
    float* out = (float*)d_out;

    if (ws_size < WS_NEEDED) {
        diag_kernel<<<1, 64, 0, stream>>>(out, (float)(ws_size >> 16));
        return;
    }

    char* wsb = (char*)d_ws;
    float* qa  = (float*)(wsb + 0);
    float* qd  = (float*)(wsb + 2048);
    float* va  = (float*)(wsb + 4096);
    float* vd  = (float*)(wsb + 6144);
    float* bqf = (float*)(wsb + 8192);
    float* bkf = (float*)(wsb + 10240);
    float* bvf = (float*)(wsb + 12288);
    ushort_t* XT = (ushort_t*)(wsb + 16384);               // 4 MB bf16 [4096][512]
    ushort_t* QT = (ushort_t*)(wsb + 16384 + 4194304);     // 4 MB bf16 [4096][512] (becomes O)
    ushort_t* KT = (ushort_t*)d_out;                        // 4 MB bf16 [4096][512]
    ushort_t* Vb = (ushort_t*)d_out + (size_t)CHAN * NTOK;  // 4 MB bf16 [512][4096]

    gn_all<<<32, 256, 0, stream>>>(x, gnw, gnb, qa, qd, va, vd);
    bias_fold<<<3, 256, 0, stream>>>(wq, wk, wv, bq, bk, bv, qd, vd, bqf, bkf, bvf);
    xt_prep<<<dim3(64, 8), 256, 0, stream>>>(x, XT);

    qkv_mfma<<<dim3(32, 12), 256, 0, stream>>>(XT, wq, wk, wv, bqf, bkf, bvf,
                                               qa, va, QT, KT, Vb);

    attn_v3<<<dim3(32, 16), 256, 0, stream>>>(QT, KT, Vb);

    oproj_mfma<<<dim3(32, 8), 256, 0, stream>>>(QT, wo, bo, x, out);
}

// Round 13
// 281.356 us; speedup vs baseline: 1.1326x; 1.1326x over previous
//
#include <hip/hip_runtime.h>

#define NTOK 4096
#define CHAN 512
#define GSIZE 65536
#define RSQRT2 0.7071067811865476f
#define QSCALE 0.2550316360552602f   // (1/sqrt(32)) * log2(e)  -> exp2 domain
#define WS_NEEDED ((size_t)(16384 + 8 * 1024 * 1024))

typedef unsigned short ushort_t;
typedef __attribute__((ext_vector_type(8))) short bf16x8;
typedef __attribute__((ext_vector_type(4))) float f32x4;

__device__ __forceinline__ ushort_t f2b(float f) {
    unsigned u = __float_as_uint(f);
    unsigned r = (u + 0x7FFFu + ((u >> 16) & 1u)) >> 16;
    return (ushort_t)r;
}
__device__ __forceinline__ unsigned pack2r(float a, float b) {
    unsigned ua = __float_as_uint(a), ub = __float_as_uint(b);
    return ((ua + 0x8000u) >> 16) | ((ub + 0x8000u) & 0xFFFF0000u);
}
__device__ __forceinline__ bf16x8 ldfrag(const ushort_t* p) {
    return __builtin_bit_cast(bf16x8, *(const uint4*)p);
}

__global__ void diag_kernel(float* out, float v) {
    if (threadIdx.x == 0 && blockIdx.x == 0) out[0] = v;
}

// ---- Fused GroupNorm: per-channel affine coeffs for qn and vn (one x pass).
__global__ __launch_bounds__(256) void gn_all(const float* __restrict__ x,
                                              const float* __restrict__ gnw,
                                              const float* __restrict__ gnb,
                                              float* __restrict__ qa,
                                              float* __restrict__ qd,
                                              float* __restrict__ va,
                                              float* __restrict__ vd) {
    int g = blockIdx.x, t = threadIdx.x;
    int cl = t >> 4, sl = t & 15;
    const float4* p = (const float4*)(x + (size_t)g * GSIZE + (size_t)cl * 4096);
    float s = 0.f, ss = 0.f;
    for (int i = 0; i < 64; i++) {
        float4 f = p[i * 16 + sl];
        s += f.x + f.y + f.z + f.w;
        ss += f.x * f.x + f.y * f.y + f.z * f.z + f.w * f.w;
    }
    #pragma unroll
    for (int off = 8; off > 0; off >>= 1) {
        s += __shfl_xor(s, off);
        ss += __shfl_xor(ss, off);
    }
    __shared__ float Sc[16], SSc[16];
    if (sl == 0) { Sc[cl] = s; SSc[cl] = ss; }
    __syncthreads();
    if (t < 16) {
        float S = Sc[t], SS = SSc[t];
        float gs = S, gss = SS;
        #pragma unroll
        for (int off = 8; off > 0; off >>= 1) {
            gs += __shfl_xor(gs, off);
            gss += __shfl_xor(gss, off);
        }
        float mu = gs * (1.f / GSIZE);
        float var = gss * (1.f / GSIZE) - mu * mu;
        float r1 = rsqrtf(var + 1e-6f);
        int c = g * 16 + t;
        float wc = gnw[c], bc = gnb[c];
        float a1 = r1 * wc;
        float d1 = bc - mu * a1;
        qa[c] = a1; qd[c] = d1;
        float S2 = a1 * S + 4096.f * d1;
        float SS2 = a1 * a1 * SS + 2.f * a1 * d1 * S + 4096.f * d1 * d1;
        float gs2 = S2, gss2 = SS2;
        #pragma unroll
        for (int off = 8; off > 0; off >>= 1) {
            gs2 += __shfl_xor(gs2, off);
            gss2 += __shfl_xor(gss2, off);
        }
        float mu2 = gs2 * (1.f / GSIZE);
        float var2 = gss2 * (1.f / GSIZE) - mu2 * mu2;
        float r2 = rsqrtf(var2 + 1e-6f);
        float a2 = r2 * wc;
        va[c] = a1 * a2;
        vd[c] = a2 * (d1 - mu2) + bc;
    }
}

// ---- Fold GN offsets into biases: b'[o] = b[o] + sum_c W[o][c]*d[c].
__global__ __launch_bounds__(256) void bias_fold(const float* __restrict__ wq,
                                                 const float* __restrict__ wk,
                                                 const float* __restrict__ wv,
                                                 const float* __restrict__ bq,
                                                 const float* __restrict__ bk,
                                                 const float* __restrict__ bv,
                                                 const float* __restrict__ qd,
                                                 const float* __restrict__ vd,
                                                 float* __restrict__ bqf,
                                                 float* __restrict__ bkf,
                                                 float* __restrict__ bvf) {
    int m = blockIdx.x, t = threadIdx.x;
    const float* W = (m == 0) ? wq : (m == 1) ? wk : wv;
    const float* b = (m == 0) ? bq : (m == 1) ? bk : bv;
    const float* d = (m == 0) ? qd : vd;
    float* outp    = (m == 0) ? bqf : (m == 1) ? bkf : bvf;
    #pragma unroll
    for (int rep = 0; rep < 2; rep++) {
        int o = rep * 256 + t;
        const float4* wr = (const float4*)(W + (size_t)o * 512);
        const float4* dr = (const float4*)d;
        float acc = 0.f;
        for (int i = 0; i < 128; i++) {
            float4 wv4 = wr[i], dv4 = dr[i];
            acc += wv4.x * dv4.x + wv4.y * dv4.y + wv4.z * dv4.z + wv4.w * dv4.w;
        }
        outp[o] = b[o] + acc;
    }
}

// ---- XT = bf16(x)^T : [4096 tok][512 chan], token-major.
__global__ __launch_bounds__(256) void xt_prep(const float* __restrict__ x,
                                               ushort_t* __restrict__ XT) {
    __shared__ float Tl[64][65];
    int t = threadIdx.x;
    int tbase = blockIdx.x << 6, cbase = blockIdx.y << 6;
    int cl = t >> 2, tq = t & 3;
    #pragma unroll
    for (int i = 0; i < 4; i++) {
        float4 f = *(const float4*)&x[(size_t)(cbase + cl) * NTOK + tbase + tq * 16 + i * 4];
        Tl[cl][tq * 16 + i * 4 + 0] = f.x;
        Tl[cl][tq * 16 + i * 4 + 1] = f.y;
        Tl[cl][tq * 16 + i * 4 + 2] = f.z;
        Tl[cl][tq * 16 + i * 4 + 3] = f.w;
    }
    __syncthreads();
    #pragma unroll
    for (int i = 0; i < 2; i++) {
        int idx = 2 * t + i;
        int row = idx >> 3, c8 = idx & 7;
        float v[8];
        #pragma unroll
        for (int j = 0; j < 8; j++) v[j] = Tl[c8 * 8 + j][row];
        uint4 u;
        u.x = pack2r(v[0], v[1]);
        u.y = pack2r(v[2], v[3]);
        u.z = pack2r(v[4], v[5]);
        u.w = pack2r(v[6], v[7]);
        *(uint4*)&XT[(size_t)(tbase + row) * 512 + cbase + c8 * 8] = u;
    }
}

// ---- QKV projection. Tile 128m x 128n, K-step 32. A = W*aff (fp32->bf16 at
// staging), B = XT copy-staged in LDS (shared by all 4 waves).
__global__ __launch_bounds__(256) void qkv_mfma(const ushort_t* __restrict__ XT,
                                                const float* __restrict__ wq,
                                                const float* __restrict__ wk,
                                                const float* __restrict__ wv,
                                                const float* __restrict__ bqf,
                                                const float* __restrict__ bkf,
                                                const float* __restrict__ bvf,
                                                const float* __restrict__ qa,
                                                const float* __restrict__ va,
                                                ushort_t* __restrict__ QT,
                                                ushort_t* __restrict__ KT,
                                                ushort_t* __restrict__ Vb) {
    __shared__ __align__(16) ushort_t Wl[128][40];
    __shared__ __align__(16) ushort_t Bn[128][40];
    __shared__ __align__(16) ushort_t Tl[128][72];
    int t = threadIdx.x;
    int nbase = blockIdx.x << 7;
    int y = blockIdx.y;
    int buf = y >> 2;
    int obase = (y & 3) << 7;
    const float* W    = (buf == 0) ? wq : (buf == 1) ? wk : wv;
    const float* bias = (buf == 0) ? bqf : (buf == 1) ? bkf : bvf;
    const float* aff  = (buf == 0) ? qa : va;

    int w = t >> 6, lane = t & 63, q15 = lane & 15, quad = lane >> 4;
    f32x4 acc[2][8];
    #pragma unroll
    for (int i = 0; i < 2; i++)
        #pragma unroll
        for (int j = 0; j < 8; j++) acc[i][j] = (f32x4){0.f, 0.f, 0.f, 0.f};

    int ml = t & 127, kg = t >> 7;         // A staging role
    int brow = t >> 1, bseg = t & 1;       // B staging role
    for (int ck = 0; ck < 512; ck += 32) {
        __syncthreads();
        {   // A: 128 rows x 32 k, fold affine, fp32->bf16
            const float* src = W + (size_t)(obase + ml) * 512 + ck + kg * 16;
            const float* ap = aff + ck + kg * 16;
            float v[16];
            #pragma unroll
            for (int i = 0; i < 4; i++) {
                float4 f = *(const float4*)(src + i * 4);
                v[i * 4 + 0] = f.x * ap[i * 4 + 0];
                v[i * 4 + 1] = f.y * ap[i * 4 + 1];
                v[i * 4 + 2] = f.z * ap[i * 4 + 2];
                v[i * 4 + 3] = f.w * ap[i * 4 + 3];
            }
            uint4 u0, u1;
            u0.x = pack2r(v[0], v[1]);   u0.y = pack2r(v[2], v[3]);
            u0.z = pack2r(v[4], v[5]);   u0.w = pack2r(v[6], v[7]);
            u1.x = pack2r(v[8], v[9]);   u1.y = pack2r(v[10], v[11]);
            u1.z = pack2r(v[12], v[13]); u1.w = pack2r(v[14], v[15]);
            *(uint4*)&Wl[ml][kg * 16] = u0;
            *(uint4*)&Wl[ml][kg * 16 + 8] = u1;
        }
        {   // B: 128 token-rows x 32 chans, pure uint4 copy from XT
            const ushort_t* src = &XT[(size_t)(nbase + brow) * 512 + ck + bseg * 16];
            uint4 u0 = *(const uint4*)(src);
            uint4 u1 = *(const uint4*)(src + 8);
            *(uint4*)&Bn[brow][bseg * 16] = u0;
            *(uint4*)&Bn[brow][bseg * 16 + 8] = u1;
        }
        __syncthreads();
        bf16x8 af0 = ldfrag(&Wl[w * 32 + q15][quad * 8]);
        bf16x8 af1 = ldfrag(&Wl[w * 32 + 16 + q15][quad * 8]);
        #pragma unroll
        for (int n8 = 0; n8 < 8; n8++) {
            bf16x8 bfv = ldfrag(&Bn[n8 * 16 + q15][quad * 8]);
            acc[0][n8] = __builtin_amdgcn_mfma_f32_16x16x32_bf16(af0, bfv, acc[0][n8], 0, 0, 0);
            acc[1][n8] = __builtin_amdgcn_mfma_f32_16x16x32_bf16(af1, bfv, acc[1][n8], 0, 0, 0);
        }
    }

    if (buf == 2) {   // V: [chan][tok]
        #pragma unroll
        for (int mi = 0; mi < 2; mi++)
            #pragma unroll
            for (int r = 0; r < 4; r++) {
                int o = obase + w * 32 + mi * 16 + quad * 4 + r;
                float bo = bias[o];
                #pragma unroll
                for (int n8 = 0; n8 < 8; n8++)
                    Vb[(size_t)o * NTOK + nbase + n8 * 16 + q15] = f2b(acc[mi][n8][r] + bo);
            }
        return;
    }

    ushort_t* dstT = (buf == 0) ? QT : KT;
    float qs = (buf == 0) ? QSCALE : 1.0f;
    for (int half = 0; half < 2; half++) {
        __syncthreads();
        if ((w >> 1) == half) {
            int wl = w & 1;
            #pragma unroll
            for (int mi = 0; mi < 2; mi++)
                #pragma unroll
                for (int r = 0; r < 4; r++) {
                    int mt = w * 32 + mi * 16 + quad * 4 + r;
                    int mloc = wl * 32 + mi * 16 + quad * 4 + r;
                    float bo = bias[obase + mt];
                    #pragma unroll
                    for (int n8 = 0; n8 < 8; n8++)
                        Tl[n8 * 16 + q15][mloc] = f2b((acc[mi][n8][r] + bo) * qs);
                }
        }
        __syncthreads();
        #pragma unroll
        for (int b = 0; b < 4; b++) {
            int j = b * 256 + t;
            int row = j >> 3, ch = j & 7;
            uint4 u = *(const uint4*)&Tl[row][ch * 8];
            *(uint4*)&dstT[(size_t)(nbase + row) * 512 + obase + half * 64 + ch * 8] = u;
        }
    }
}

// ---- Attention v4: 64q/block, 4 waves x 16q, K-tile 64, copy-only LDS
// staging (KT token-major, V chan-major), Q-frags direct-global, exp2 softmax,
// O overwrites QT rows in place (token-major).
__global__ __launch_bounds__(256) void attn_v4(ushort_t* __restrict__ QT,
                                               const ushort_t* __restrict__ KT,
                                               const ushort_t* __restrict__ V) {
    __shared__ __align__(16) ushort_t Kt[64][40];     // [key][32 chans]
    __shared__ __align__(16) ushort_t Vt[32][72];     // [d][64 keys]
    __shared__ __align__(16) unsigned Plu[4][16][36]; // per-wave [q][key-pairs]
    int h = blockIdx.y;
    int t = threadIdx.x;
    int w = t >> 6, lane = t & 63, q15 = lane & 15, quad = lane >> 4;
    int qbase = blockIdx.x << 6;
    int hc = h * 32;
    const ushort_t* Vh = V + (size_t)hc * NTOK;

    // One Q fragment per wave (16 queries), direct from global (read once).
    bf16x8 qf = ldfrag(&QT[(size_t)(qbase + w * 16 + q15) * 512 + hc + quad * 8]);

    f32x4 o0 = {0.f, 0.f, 0.f, 0.f};
    f32x4 o1 = {0.f, 0.f, 0.f, 0.f};
    float l = 0.f;

    int krow = t >> 2, kseg = t & 3;       // K staging role
    int vrow = t >> 3, vseg = t & 7;       // V staging role
    for (int j0 = 0; j0 < NTOK; j0 += 64) {
        __syncthreads();
        *(uint4*)&Kt[krow][kseg * 8] =
            *(const uint4*)&KT[(size_t)(j0 + krow) * 512 + hc + kseg * 8];
        *(uint4*)&Vt[vrow][vseg * 8] =
            *(const uint4*)&Vh[(size_t)vrow * NTOK + j0 + vseg * 8];
        __syncthreads();

        f32x4 st[4];
        #pragma unroll
        for (int kt = 0; kt < 4; kt++) {
            bf16x8 kf = ldfrag(&Kt[kt * 16 + q15][quad * 8]);
            f32x4 z = {0.f, 0.f, 0.f, 0.f};
            st[kt] = __builtin_amdgcn_mfma_f32_16x16x32_bf16(kf, qf, z, 0, 0, 0);
        }

        #pragma unroll
        for (int kt = 0; kt < 4; kt++)
            #pragma unroll
            for (int r = 0; r < 4; r++) {
                float e = exp2f(st[kt][r]);
                st[kt][r] = e;
                l += e;
            }

        asm volatile("" ::: "memory");
        #pragma unroll
        for (int kt = 0; kt < 4; kt++) {
            uint2 pp;
            pp.x = pack2r(st[kt][0], st[kt][1]);
            pp.y = pack2r(st[kt][2], st[kt][3]);
            *(uint2*)&Plu[w][q15][kt * 8 + quad * 2] = pp;
        }
        asm volatile("" ::: "memory");

        #pragma unroll
        for (int kc = 0; kc < 2; kc++) {
            uint4 pu = *(const uint4*)&Plu[w][q15][kc * 16 + quad * 4];
            bf16x8 pf = __builtin_bit_cast(bf16x8, pu);
            bf16x8 v0 = ldfrag(&Vt[q15][kc * 32 + quad * 8]);
            bf16x8 v1 = ldfrag(&Vt[16 + q15][kc * 32 + quad * 8]);
            o0 = __builtin_amdgcn_mfma_f32_16x16x32_bf16(pf, v0, o0, 0, 0, 0);
            o1 = __builtin_amdgcn_mfma_f32_16x16x32_bf16(pf, v1, o1, 0, 0, 0);
        }
    }

    l += __shfl_xor(l, 16);
    l += __shfl_xor(l, 32);
    float li = 1.f / l;
    #pragma unroll
    for (int r = 0; r < 4; r++) {
        int q = quad * 4 + r;
        float lr = __shfl(li, q);
        QT[(size_t)(qbase + w * 16 + q) * 512 + hc + q15]      = f2b(o0[r] * lr);
        QT[(size_t)(qbase + w * 16 + q) * 512 + hc + 16 + q15] = f2b(o1[r] * lr);
    }
}

// ---- Output projection: A = wo fp32->bf16 staged; B = OT copy-staged.
// Epilogue: (acc + bias + x) * RSQRT2, fp32.
__global__ __launch_bounds__(256) void oproj_mfma(const ushort_t* __restrict__ OT,
                                                  const float* __restrict__ wo,
                                                  const float* __restrict__ bo,
                                                  const float* __restrict__ x,
                                                  float* __restrict__ out) {
    __shared__ __align__(16) ushort_t Wl[64][40];
    __shared__ __align__(16) ushort_t Bn[128][40];
    int t = threadIdx.x;
    int nbase = blockIdx.x << 7;
    int obase = blockIdx.y << 6;
    int w = t >> 6, lane = t & 63, q15 = lane & 15, quad = lane >> 4;

    f32x4 acc[8];
    #pragma unroll
    for (int i = 0; i < 8; i++) acc[i] = (f32x4){0.f, 0.f, 0.f, 0.f};

    int ml = t & 63, kg = t >> 6;
    int brow = t >> 1, bseg = t & 1;
    for (int ck = 0; ck < 512; ck += 32) {
        __syncthreads();
        {
            const float* src = wo + (size_t)(obase + ml) * 512 + ck + kg * 8;
            float4 f0 = *(const float4*)(src + 0);
            float4 f1 = *(const float4*)(src + 4);
            uint4 u;
            u.x = pack2r(f0.x, f0.y); u.y = pack2r(f0.z, f0.w);
            u.z = pack2r(f1.x, f1.y); u.w = pack2r(f1.z, f1.w);
            *(uint4*)&Wl[ml][kg * 8] = u;
        }
        {
            const ushort_t* src = &OT[(size_t)(nbase + brow) * 512 + ck + bseg * 16];
            uint4 u0 = *(const uint4*)(src);
            uint4 u1 = *(const uint4*)(src + 8);
            *(uint4*)&Bn[brow][bseg * 16] = u0;
            *(uint4*)&Bn[brow][bseg * 16 + 8] = u1;
        }
        __syncthreads();
        bf16x8 af = ldfrag(&Wl[w * 16 + q15][quad * 8]);
        #pragma unroll
        for (int n8 = 0; n8 < 8; n8++) {
            bf16x8 bfv = ldfrag(&Bn[n8 * 16 + q15][quad * 8]);
            acc[n8] = __builtin_amdgcn_mfma_f32_16x16x32_bf16(af, bfv, acc[n8], 0, 0, 0);
        }
    }

    #pragma unroll
    for (int r = 0; r < 4; r++) {
        int o = obase + w * 16 + quad * 4 + r;
        float b = bo[o];
        #pragma unroll
        for (int n8 = 0; n8 < 8; n8++) {
            size_t idx = (size_t)o * NTOK + nbase + n8 * 16 + q15;
            out[idx] = (acc[n8][r] + b + x[idx]) * RSQRT2;
        }
    }
}

extern "C" void kernel_launch(void* const* d_in, const int* in_sizes, int n_in,
                              void* d_out, int out_size, void* d_ws, size_t ws_size,
                              hipStream_t stream) {
    const float* x   = (const float*)d_in[0];
    const float* gnw = (const float*)d_in[1];
    const float* gnb = (const float*)d_in[2];
    const float* wq  = (const float*)d_in[3];
    const float* bq  = (const float*)d_in[4];
    const float* wk  = (const float*)d_in[5];
    const float* bk  = (const float*)d_in[6];
    const float* wv  = (const float*)d_in[7];
    const float* bv  = (const float*)d_in[8];
    const float* wo  = (const float*)d_in[9];
    const float* bo  = (const float*)d_in[10];
    float* out = (float*)d_out;

    if (ws_size < WS_NEEDED) {
        diag_kernel<<<1, 64, 0, stream>>>(out, (float)(ws_size >> 16));
        return;
    }

    char* wsb = (char*)d_ws;
    float* qa  = (float*)(wsb + 0);
    float* qd  = (float*)(wsb + 2048);
    float* va  = (float*)(wsb + 4096);
    float* vd  = (float*)(wsb + 6144);
    float* bqf = (float*)(wsb + 8192);
    float* bkf = (float*)(wsb + 10240);
    float* bvf = (float*)(wsb + 12288);
    ushort_t* XT = (ushort_t*)(wsb + 16384);               // 4 MB bf16 [4096][512]
    ushort_t* QT = (ushort_t*)(wsb + 16384 + 4194304);     // 4 MB bf16 [4096][512] (becomes O)
    ushort_t* KT = (ushort_t*)d_out;                        // 4 MB bf16 [4096][512]
    ushort_t* Vb = (ushort_t*)d_out + (size_t)CHAN * NTOK;  // 4 MB bf16 [512][4096]

    gn_all<<<32, 256, 0, stream>>>(x, gnw, gnb, qa, qd, va, vd);
    bias_fold<<<3, 256, 0, stream>>>(wq, wk, wv, bq, bk, bv, qd, vd, bqf, bkf, bvf);
    xt_prep<<<dim3(64, 8), 256, 0, stream>>>(x, XT);

    qkv_mfma<<<dim3(32, 12), 256, 0, stream>>>(XT, wq, wk, wv, bqf, bkf, bvf,
                                               qa, va, QT, KT, Vb);

    attn_v4<<<dim3(64, 16), 256, 0, stream>>>(QT, KT, Vb);

    oproj_mfma<<<dim3(32, 8), 256, 0, stream>>>(QT, wo, bo, x, out);
}

// Round 14
// 230.227 us; speedup vs baseline: 1.3841x; 1.2221x over previous
//
#include <hip/hip_runtime.h>

#define NTOK 4096
#define CHAN 512
#define GSIZE 65536
#define RSQRT2 0.7071067811865476f
#define SCALE 0.17677669529663687f   // 1/sqrt(32); softmax uses __expf
#define WS_NEEDED ((size_t)(16384 + 8 * 1024 * 1024))

typedef unsigned short ushort_t;
typedef __attribute__((ext_vector_type(8))) short bf16x8;
typedef __attribute__((ext_vector_type(8))) _Float16 f16x8;
typedef __attribute__((ext_vector_type(4))) float f32x4;

__device__ __forceinline__ ushort_t f2b(float f) {
    unsigned u = __float_as_uint(f);
    unsigned r = (u + 0x7FFFu + ((u >> 16) & 1u)) >> 16;
    return (ushort_t)r;
}
__device__ __forceinline__ unsigned pack2r(float a, float b) {
    unsigned ua = __float_as_uint(a), ub = __float_as_uint(b);
    return ((ua + 0x8000u) >> 16) | ((ub + 0x8000u) & 0xFFFF0000u);
}
__device__ __forceinline__ unsigned packh2(float a, float b) {
    return __builtin_bit_cast(unsigned, __builtin_amdgcn_cvt_pkrtz(a, b));
}
__device__ __forceinline__ ushort_t f2h(float f) {
    return (ushort_t)(packh2(f, f) & 0xFFFFu);
}
__device__ __forceinline__ bf16x8 ldfrag(const ushort_t* p) {
    return __builtin_bit_cast(bf16x8, *(const uint4*)p);
}
__device__ __forceinline__ f16x8 ldfragh(const ushort_t* p) {
    return __builtin_bit_cast(f16x8, *(const uint4*)p);
}

__global__ void diag_kernel(float* out, float v) {
    if (threadIdx.x == 0 && blockIdx.x == 0) out[0] = v;
}

// ---- Fused GroupNorm: per-channel affine coeffs for qn and vn (one x pass).
__global__ __launch_bounds__(256) void gn_all(const float* __restrict__ x,
                                              const float* __restrict__ gnw,
                                              const float* __restrict__ gnb,
                                              float* __restrict__ qa,
                                              float* __restrict__ qd,
                                              float* __restrict__ va,
                                              float* __restrict__ vd) {
    int g = blockIdx.x, t = threadIdx.x;
    int cl = t >> 4, sl = t & 15;
    const float4* p = (const float4*)(x + (size_t)g * GSIZE + (size_t)cl * 4096);
    float s = 0.f, ss = 0.f;
    for (int i = 0; i < 64; i++) {
        float4 f = p[i * 16 + sl];
        s += f.x + f.y + f.z + f.w;
        ss += f.x * f.x + f.y * f.y + f.z * f.z + f.w * f.w;
    }
    #pragma unroll
    for (int off = 8; off > 0; off >>= 1) {
        s += __shfl_xor(s, off);
        ss += __shfl_xor(ss, off);
    }
    __shared__ float Sc[16], SSc[16];
    if (sl == 0) { Sc[cl] = s; SSc[cl] = ss; }
    __syncthreads();
    if (t < 16) {
        float S = Sc[t], SS = SSc[t];
        float gs = S, gss = SS;
        #pragma unroll
        for (int off = 8; off > 0; off >>= 1) {
            gs += __shfl_xor(gs, off);
            gss += __shfl_xor(gss, off);
        }
        float mu = gs * (1.f / GSIZE);
        float var = gss * (1.f / GSIZE) - mu * mu;
        float r1 = rsqrtf(var + 1e-6f);
        int c = g * 16 + t;
        float wc = gnw[c], bc = gnb[c];
        float a1 = r1 * wc;
        float d1 = bc - mu * a1;
        qa[c] = a1; qd[c] = d1;
        float S2 = a1 * S + 4096.f * d1;
        float SS2 = a1 * a1 * SS + 2.f * a1 * d1 * S + 4096.f * d1 * d1;
        float gs2 = S2, gss2 = SS2;
        #pragma unroll
        for (int off = 8; off > 0; off >>= 1) {
            gs2 += __shfl_xor(gs2, off);
            gss2 += __shfl_xor(gss2, off);
        }
        float mu2 = gs2 * (1.f / GSIZE);
        float var2 = gss2 * (1.f / GSIZE) - mu2 * mu2;
        float r2 = rsqrtf(var2 + 1e-6f);
        float a2 = r2 * wc;
        va[c] = a1 * a2;
        vd[c] = a2 * (d1 - mu2) + bc;
    }
}

// ---- Fold GN offsets into biases: b'[o] = b[o] + sum_c W[o][c]*d[c].
// Grid 384 blocks x 256 (one wave per output row, 1536 rows total).
__global__ __launch_bounds__(256) void bias_fold(const float* __restrict__ wq,
                                                 const float* __restrict__ wk,
                                                 const float* __restrict__ wv,
                                                 const float* __restrict__ bq,
                                                 const float* __restrict__ bk,
                                                 const float* __restrict__ bv,
                                                 const float* __restrict__ qd,
                                                 const float* __restrict__ vd,
                                                 float* __restrict__ bqf,
                                                 float* __restrict__ bkf,
                                                 float* __restrict__ bvf) {
    int row = blockIdx.x * 4 + (threadIdx.x >> 6);   // 0..1535
    int lane = threadIdx.x & 63;
    int m = row >> 9;
    int o = row & 511;
    const float* W = (m == 0) ? wq : (m == 1) ? wk : wv;
    const float* b = (m == 0) ? bq : (m == 1) ? bk : bv;
    const float* d = (m == 0) ? qd : vd;
    float* outp    = (m == 0) ? bqf : (m == 1) ? bkf : bvf;
    const float4* wr = (const float4*)(W + (size_t)o * 512) + lane * 2;
    const float4* dr = (const float4*)d + lane * 2;
    float4 a0 = wr[0], a1 = wr[1], d0 = dr[0], d1 = dr[1];
    float acc = a0.x * d0.x + a0.y * d0.y + a0.z * d0.z + a0.w * d0.w
              + a1.x * d1.x + a1.y * d1.y + a1.z * d1.z + a1.w * d1.w;
    #pragma unroll
    for (int off = 32; off > 0; off >>= 1) acc += __shfl_xor(acc, off);
    if (lane == 0) outp[o] = b[o] + acc;
}

// ---- XT = bf16(x)^T : [4096 tok][512 chan], token-major.
__global__ __launch_bounds__(256) void xt_prep(const float* __restrict__ x,
                                               ushort_t* __restrict__ XT) {
    __shared__ float Tl[64][65];
    int t = threadIdx.x;
    int tbase = blockIdx.x << 6, cbase = blockIdx.y << 6;
    int cl = t >> 2, tq = t & 3;
    #pragma unroll
    for (int i = 0; i < 4; i++) {
        float4 f = *(const float4*)&x[(size_t)(cbase + cl) * NTOK + tbase + tq * 16 + i * 4];
        Tl[cl][tq * 16 + i * 4 + 0] = f.x;
        Tl[cl][tq * 16 + i * 4 + 1] = f.y;
        Tl[cl][tq * 16 + i * 4 + 2] = f.z;
        Tl[cl][tq * 16 + i * 4 + 3] = f.w;
    }
    __syncthreads();
    #pragma unroll
    for (int i = 0; i < 2; i++) {
        int idx = 2 * t + i;
        int row = idx >> 3, c8 = idx & 7;
        float v[8];
        #pragma unroll
        for (int j = 0; j < 8; j++) v[j] = Tl[c8 * 8 + j][row];
        uint4 u;
        u.x = pack2r(v[0], v[1]);
        u.y = pack2r(v[2], v[3]);
        u.z = pack2r(v[4], v[5]);
        u.w = pack2r(v[6], v[7]);
        *(uint4*)&XT[(size_t)(tbase + row) * 512 + cbase + c8 * 8] = u;
    }
}

// ---- QKV projection. Tile 128m x 128n, K-step 32. A = W*aff (fp32->bf16 at
// staging), B = XT copy-staged. Q -> QT bf16 (pre-scaled); K -> KT bf16;
// V -> f16 [chan][tok] (PV runs in f16).
__global__ __launch_bounds__(256) void qkv_mfma(const ushort_t* __restrict__ XT,
                                                const float* __restrict__ wq,
                                                const float* __restrict__ wk,
                                                const float* __restrict__ wv,
                                                const float* __restrict__ bqf,
                                                const float* __restrict__ bkf,
                                                const float* __restrict__ bvf,
                                                const float* __restrict__ qa,
                                                const float* __restrict__ va,
                                                ushort_t* __restrict__ QT,
                                                ushort_t* __restrict__ KT,
                                                ushort_t* __restrict__ Vb) {
    __shared__ __align__(16) ushort_t Wl[128][40];
    __shared__ __align__(16) ushort_t Bn[128][40];
    __shared__ __align__(16) ushort_t Tl[128][72];
    int t = threadIdx.x;
    int nbase = blockIdx.x << 7;
    int y = blockIdx.y;
    int buf = y >> 2;
    int obase = (y & 3) << 7;
    const float* W    = (buf == 0) ? wq : (buf == 1) ? wk : wv;
    const float* bias = (buf == 0) ? bqf : (buf == 1) ? bkf : bvf;
    const float* aff  = (buf == 0) ? qa : va;

    int w = t >> 6, lane = t & 63, q15 = lane & 15, quad = lane >> 4;
    f32x4 acc[2][8];
    #pragma unroll
    for (int i = 0; i < 2; i++)
        #pragma unroll
        for (int j = 0; j < 8; j++) acc[i][j] = (f32x4){0.f, 0.f, 0.f, 0.f};

    int ml = t & 127, kg = t >> 7;
    int brow = t >> 1, bseg = t & 1;
    for (int ck = 0; ck < 512; ck += 32) {
        __syncthreads();
        {   // A: 128 rows x 32 k, fold affine, fp32->bf16
            const float* src = W + (size_t)(obase + ml) * 512 + ck + kg * 16;
            const float* ap = aff + ck + kg * 16;
            float v[16];
            #pragma unroll
            for (int i = 0; i < 4; i++) {
                float4 f = *(const float4*)(src + i * 4);
                v[i * 4 + 0] = f.x * ap[i * 4 + 0];
                v[i * 4 + 1] = f.y * ap[i * 4 + 1];
                v[i * 4 + 2] = f.z * ap[i * 4 + 2];
                v[i * 4 + 3] = f.w * ap[i * 4 + 3];
            }
            uint4 u0, u1;
            u0.x = pack2r(v[0], v[1]);   u0.y = pack2r(v[2], v[3]);
            u0.z = pack2r(v[4], v[5]);   u0.w = pack2r(v[6], v[7]);
            u1.x = pack2r(v[8], v[9]);   u1.y = pack2r(v[10], v[11]);
            u1.z = pack2r(v[12], v[13]); u1.w = pack2r(v[14], v[15]);
            *(uint4*)&Wl[ml][kg * 16] = u0;
            *(uint4*)&Wl[ml][kg * 16 + 8] = u1;
        }
        {   // B: pure uint4 copy from XT
            const ushort_t* src = &XT[(size_t)(nbase + brow) * 512 + ck + bseg * 16];
            uint4 u0 = *(const uint4*)(src);
            uint4 u1 = *(const uint4*)(src + 8);
            *(uint4*)&Bn[brow][bseg * 16] = u0;
            *(uint4*)&Bn[brow][bseg * 16 + 8] = u1;
        }
        __syncthreads();
        bf16x8 af0 = ldfrag(&Wl[w * 32 + q15][quad * 8]);
        bf16x8 af1 = ldfrag(&Wl[w * 32 + 16 + q15][quad * 8]);
        #pragma unroll
        for (int n8 = 0; n8 < 8; n8++) {
            bf16x8 bfv = ldfrag(&Bn[n8 * 16 + q15][quad * 8]);
            acc[0][n8] = __builtin_amdgcn_mfma_f32_16x16x32_bf16(af0, bfv, acc[0][n8], 0, 0, 0);
            acc[1][n8] = __builtin_amdgcn_mfma_f32_16x16x32_bf16(af1, bfv, acc[1][n8], 0, 0, 0);
        }
    }

    if (buf == 2) {   // V: f16 [chan][tok]
        #pragma unroll
        for (int mi = 0; mi < 2; mi++)
            #pragma unroll
            for (int r = 0; r < 4; r++) {
                int o = obase + w * 32 + mi * 16 + quad * 4 + r;
                float bo = bias[o];
                #pragma unroll
                for (int n8 = 0; n8 < 8; n8++)
                    Vb[(size_t)o * NTOK + nbase + n8 * 16 + q15] = f2h(acc[mi][n8][r] + bo);
            }
        return;
    }

    ushort_t* dstT = (buf == 0) ? QT : KT;
    float qs = (buf == 0) ? SCALE : 1.0f;
    for (int half = 0; half < 2; half++) {
        __syncthreads();
        if ((w >> 1) == half) {
            int wl = w & 1;
            #pragma unroll
            for (int mi = 0; mi < 2; mi++)
                #pragma unroll
                for (int r = 0; r < 4; r++) {
                    int mt = w * 32 + mi * 16 + quad * 4 + r;
                    int mloc = wl * 32 + mi * 16 + quad * 4 + r;
                    float bo = bias[obase + mt];
                    #pragma unroll
                    for (int n8 = 0; n8 < 8; n8++)
                        Tl[n8 * 16 + q15][mloc] = f2b((acc[mi][n8][r] + bo) * qs);
                }
        }
        __syncthreads();
        #pragma unroll
        for (int b = 0; b < 4; b++) {
            int j = b * 256 + t;
            int row = j >> 3, ch = j & 7;
            uint4 u = *(const uint4*)&Tl[row][ch * 8];
            *(uint4*)&dstT[(size_t)(nbase + row) * 512 + obase + half * 64 + ch * 8] = u;
        }
    }
}

// ---- Attention v5: 64q/block, 4 waves x 16q, K-tile 64, copy-only staging.
// QK in bf16; softmax via __expf (native v_exp); P packed to f16 via cvt_pkrtz;
// PV + l (ones-operand) in f16 MFMA. l lands in the same reg index as O ->
// no shuffles. O overwrites QT rows (bf16, token-major).
__global__ __launch_bounds__(256) void attn_v5(ushort_t* __restrict__ QT,
                                               const ushort_t* __restrict__ KT,
                                               const ushort_t* __restrict__ V) {
    __shared__ __align__(16) ushort_t Kt[64][40];     // [key][32 chans] bf16
    __shared__ __align__(16) ushort_t Vt[32][72];     // [d][64 keys] f16
    __shared__ __align__(16) unsigned Plu[4][16][36]; // per-wave [q][key-pairs] f16
    int h = blockIdx.y;
    int t = threadIdx.x;
    int w = t >> 6, lane = t & 63, q15 = lane & 15, quad = lane >> 4;
    int qbase = blockIdx.x << 6;
    int hc = h * 32;
    const ushort_t* Vh = V + (size_t)hc * NTOK;

    bf16x8 qf = ldfrag(&QT[(size_t)(qbase + w * 16 + q15) * 512 + hc + quad * 8]);

    const uint4 onesu = {0x3C003C00u, 0x3C003C00u, 0x3C003C00u, 0x3C003C00u};
    const f16x8 ones = __builtin_bit_cast(f16x8, onesu);

    f32x4 o0 = {0.f, 0.f, 0.f, 0.f};
    f32x4 o1 = {0.f, 0.f, 0.f, 0.f};
    f32x4 lacc = {0.f, 0.f, 0.f, 0.f};

    int krow = t >> 2, kseg = t & 3;
    int vrow = t >> 3, vseg = t & 7;
    for (int j0 = 0; j0 < NTOK; j0 += 64) {
        __syncthreads();
        *(uint4*)&Kt[krow][kseg * 8] =
            *(const uint4*)&KT[(size_t)(j0 + krow) * 512 + hc + kseg * 8];
        *(uint4*)&Vt[vrow][vseg * 8] =
            *(const uint4*)&Vh[(size_t)vrow * NTOK + j0 + vseg * 8];
        __syncthreads();

        f32x4 st[4];
        #pragma unroll
        for (int kt = 0; kt < 4; kt++) {
            bf16x8 kf = ldfrag(&Kt[kt * 16 + q15][quad * 8]);
            f32x4 z = {0.f, 0.f, 0.f, 0.f};
            st[kt] = __builtin_amdgcn_mfma_f32_16x16x32_bf16(kf, qf, z, 0, 0, 0);
        }

        #pragma unroll
        for (int kt = 0; kt < 4; kt++)
            #pragma unroll
            for (int r = 0; r < 4; r++)
                st[kt][r] = __expf(st[kt][r]);

        asm volatile("" ::: "memory");
        #pragma unroll
        for (int kt = 0; kt < 4; kt++) {
            uint2 pp;
            pp.x = packh2(st[kt][0], st[kt][1]);
            pp.y = packh2(st[kt][2], st[kt][3]);
            *(uint2*)&Plu[w][q15][kt * 8 + quad * 2] = pp;
        }
        asm volatile("" ::: "memory");

        #pragma unroll
        for (int kc = 0; kc < 2; kc++) {
            uint4 pu = *(const uint4*)&Plu[w][q15][kc * 16 + quad * 4];
            f16x8 pf = __builtin_bit_cast(f16x8, pu);
            f16x8 v0 = ldfragh(&Vt[q15][kc * 32 + quad * 8]);
            f16x8 v1 = ldfragh(&Vt[16 + q15][kc * 32 + quad * 8]);
            o0 = __builtin_amdgcn_mfma_f32_16x16x32_f16(pf, v0, o0, 0, 0, 0);
            o1 = __builtin_amdgcn_mfma_f32_16x16x32_f16(pf, v1, o1, 0, 0, 0);
            lacc = __builtin_amdgcn_mfma_f32_16x16x32_f16(pf, ones, lacc, 0, 0, 0);
        }
    }

    // lacc[r] = total l for q = quad*4 + r (same index as o0/o1 rows).
    #pragma unroll
    for (int r = 0; r < 4; r++) {
        float li = 1.f / lacc[r];
        int q = quad * 4 + r;
        QT[(size_t)(qbase + w * 16 + q) * 512 + hc + q15]      = f2b(o0[r] * li);
        QT[(size_t)(qbase + w * 16 + q) * 512 + hc + 16 + q15] = f2b(o1[r] * li);
    }
}

// ---- Output projection: A = wo fp32->bf16 staged; B = OT copy-staged.
__global__ __launch_bounds__(256) void oproj_mfma(const ushort_t* __restrict__ OT,
                                                  const float* __restrict__ wo,
                                                  const float* __restrict__ bo,
                                                  const float* __restrict__ x,
                                                  float* __restrict__ out) {
    __shared__ __align__(16) ushort_t Wl[64][40];
    __shared__ __align__(16) ushort_t Bn[128][40];
    int t = threadIdx.x;
    int nbase = blockIdx.x << 7;
    int obase = blockIdx.y << 6;
    int w = t >> 6, lane = t & 63, q15 = lane & 15, quad = lane >> 4;

    f32x4 acc[8];
    #pragma unroll
    for (int i = 0; i < 8; i++) acc[i] = (f32x4){0.f, 0.f, 0.f, 0.f};

    int ml = t & 63, kg = t >> 6;
    int brow = t >> 1, bseg = t & 1;
    for (int ck = 0; ck < 512; ck += 32) {
        __syncthreads();
        {
            const float* src = wo + (size_t)(obase + ml) * 512 + ck + kg * 8;
            float4 f0 = *(const float4*)(src + 0);
            float4 f1 = *(const float4*)(src + 4);
            uint4 u;
            u.x = pack2r(f0.x, f0.y); u.y = pack2r(f0.z, f0.w);
            u.z = pack2r(f1.x, f1.y); u.w = pack2r(f1.z, f1.w);
            *(uint4*)&Wl[ml][kg * 8] = u;
        }
        {
            const ushort_t* src = &OT[(size_t)(nbase + brow) * 512 + ck + bseg * 16];
            uint4 u0 = *(const uint4*)(src);
            uint4 u1 = *(const uint4*)(src + 8);
            *(uint4*)&Bn[brow][bseg * 16] = u0;
            *(uint4*)&Bn[brow][bseg * 16 + 8] = u1;
        }
        __syncthreads();
        bf16x8 af = ldfrag(&Wl[w * 16 + q15][quad * 8]);
        #pragma unroll
        for (int n8 = 0; n8 < 8; n8++) {
            bf16x8 bfv = ldfrag(&Bn[n8 * 16 + q15][quad * 8]);
            acc[n8] = __builtin_amdgcn_mfma_f32_16x16x32_bf16(af, bfv, acc[n8], 0, 0, 0);
        }
    }

    #pragma unroll
    for (int r = 0; r < 4; r++) {
        int o = obase + w * 16 + quad * 4 + r;
        float b = bo[o];
        #pragma unroll
        for (int n8 = 0; n8 < 8; n8++) {
            size_t idx = (size_t)o * NTOK + nbase + n8 * 16 + q15;
            out[idx] = (acc[n8][r] + b + x[idx]) * RSQRT2;
        }
    }
}

extern "C" void kernel_launch(void* const* d_in, const int* in_sizes, int n_in,
                              void* d_out, int out_size, void* d_ws, size_t ws_size,
                              hipStream_t stream) {
    const float* x   = (const float*)d_in[0];
    const float* gnw = (const float*)d_in[1];
    const float* gnb = (const float*)d_in[2];
    const float* wq  = (const float*)d_in[3];
    const float* bq  = (const float*)d_in[4];
    const float* wk  = (const float*)d_in[5];
    const float* bk  = (const float*)d_in[6];
    const float* wv  = (const float*)d_in[7];
    const float* bv  = (const float*)d_in[8];
    const float* wo  = (const float*)d_in[9];
    const float* bo  = (const float*)d_in[10];
    float* out = (float*)d_out;

    if (ws_size < WS_NEEDED) {
        diag_kernel<<<1, 64, 0, stream>>>(out, (float)(ws_size >> 16));
        return;
    }

    char* wsb = (char*)d_ws;
    float* qa  = (float*)(wsb + 0);
    float* qd  = (float*)(wsb + 2048);
    float* va  = (float*)(wsb + 4096);
    float* vd  = (float*)(wsb + 6144);
    float* bqf = (float*)(wsb + 8192);
    float* bkf = (float*)(wsb + 10240);
    float* bvf = (float*)(wsb + 12288);
    ushort_t* XT = (ushort_t*)(wsb + 16384);               // 4 MB bf16 [4096][512]
    ushort_t* QT = (ushort_t*)(wsb + 16384 + 4194304);     // 4 MB bf16 (becomes O)
    ushort_t* KT = (ushort_t*)d_out;                        // 4 MB bf16 [4096][512]
    ushort_t* Vb = (ushort_t*)d_out + (size_t)CHAN * NTOK;  // 4 MB f16 [512][4096]

    gn_all<<<32, 256, 0, stream>>>(x, gnw, gnb, qa, qd, va, vd);
    bias_fold<<<384, 256, 0, stream>>>(wq, wk, wv, bq, bk, bv, qd, vd, bqf, bkf, bvf);
    xt_prep<<<dim3(64, 8), 256, 0, stream>>>(x, XT);

    qkv_mfma<<<dim3(32, 12), 256, 0, stream>>>(XT, wq, wk, wv, bqf, bkf, bvf,
                                               qa, va, QT, KT, Vb);

    attn_v5<<<dim3(64, 16), 256, 0, stream>>>(QT, KT, Vb);

    oproj_mfma<<<dim3(32, 8), 256, 0, stream>>>(QT, wo, bo, x, out);
}

// Round 16
// 220.709 us; speedup vs baseline: 1.4438x; 1.0431x over previous
//
#include <hip/hip_runtime.h>

#define NTOK 4096
#define CHAN 512
#define GSIZE 65536
#define RSQRT2 0.7071067811865476f
#define SCALE 0.17677669529663687f   // 1/sqrt(32); softmax uses __expf
#define WS_NEEDED ((size_t)(16384 + 8 * 1024 * 1024))

typedef unsigned short ushort_t;
typedef __attribute__((ext_vector_type(8))) short bf16x8;
typedef __attribute__((ext_vector_type(8))) _Float16 f16x8;
typedef __attribute__((ext_vector_type(4))) float f32x4;

__device__ __forceinline__ ushort_t f2b(float f) {
    unsigned u = __float_as_uint(f);
    unsigned r = (u + 0x7FFFu + ((u >> 16) & 1u)) >> 16;
    return (ushort_t)r;
}
__device__ __forceinline__ unsigned pack2r(float a, float b) {
    unsigned ua = __float_as_uint(a), ub = __float_as_uint(b);
    return ((ua + 0x8000u) >> 16) | ((ub + 0x8000u) & 0xFFFF0000u);
}
__device__ __forceinline__ unsigned packh2(float a, float b) {
    return __builtin_bit_cast(unsigned, __builtin_amdgcn_cvt_pkrtz(a, b));
}
__device__ __forceinline__ ushort_t f2h(float f) {
    return (ushort_t)(packh2(f, f) & 0xFFFFu);
}
__device__ __forceinline__ bf16x8 ldfrag(const ushort_t* p) {
    return __builtin_bit_cast(bf16x8, *(const uint4*)p);
}
__device__ __forceinline__ f16x8 ldfragh(const ushort_t* p) {
    return __builtin_bit_cast(f16x8, *(const uint4*)p);
}

__global__ void diag_kernel(float* out, float v) {
    if (threadIdx.x == 0 && blockIdx.x == 0) out[0] = v;
}

// ---- Fused GroupNorm: per-channel affine coeffs for qn and vn (one x pass).
__global__ __launch_bounds__(256) void gn_all(const float* __restrict__ x,
                                              const float* __restrict__ gnw,
                                              const float* __restrict__ gnb,
                                              float* __restrict__ qa,
                                              float* __restrict__ qd,
                                              float* __restrict__ va,
                                              float* __restrict__ vd) {
    int g = blockIdx.x, t = threadIdx.x;
    int cl = t >> 4, sl = t & 15;
    const float4* p = (const float4*)(x + (size_t)g * GSIZE + (size_t)cl * 4096);
    float s = 0.f, ss = 0.f;
    for (int i = 0; i < 64; i++) {
        float4 f = p[i * 16 + sl];
        s += f.x + f.y + f.z + f.w;
        ss += f.x * f.x + f.y * f.y + f.z * f.z + f.w * f.w;
    }
    #pragma unroll
    for (int off = 8; off > 0; off >>= 1) {
        s += __shfl_xor(s, off);
        ss += __shfl_xor(ss, off);
    }
    __shared__ float Sc[16], SSc[16];
    if (sl == 0) { Sc[cl] = s; SSc[cl] = ss; }
    __syncthreads();
    if (t < 16) {
        float S = Sc[t], SS = SSc[t];
        float gs = S, gss = SS;
        #pragma unroll
        for (int off = 8; off > 0; off >>= 1) {
            gs += __shfl_xor(gs, off);
            gss += __shfl_xor(gss, off);
        }
        float mu = gs * (1.f / GSIZE);
        float var = gss * (1.f / GSIZE) - mu * mu;
        float r1 = rsqrtf(var + 1e-6f);
        int c = g * 16 + t;
        float wc = gnw[c], bc = gnb[c];
        float a1 = r1 * wc;
        float d1 = bc - mu * a1;
        qa[c] = a1; qd[c] = d1;
        float S2 = a1 * S + 4096.f * d1;
        float SS2 = a1 * a1 * SS + 2.f * a1 * d1 * S + 4096.f * d1 * d1;
        float gs2 = S2, gss2 = SS2;
        #pragma unroll
        for (int off = 8; off > 0; off >>= 1) {
            gs2 += __shfl_xor(gs2, off);
            gss2 += __shfl_xor(gss2, off);
        }
        float mu2 = gs2 * (1.f / GSIZE);
        float var2 = gss2 * (1.f / GSIZE) - mu2 * mu2;
        float r2 = rsqrtf(var2 + 1e-6f);
        float a2 = r2 * wc;
        va[c] = a1 * a2;
        vd[c] = a2 * (d1 - mu2) + bc;
    }
}

// ---- Fold GN offsets into biases: b'[o] = b[o] + sum_c W[o][c]*d[c].
__global__ __launch_bounds__(256) void bias_fold(const float* __restrict__ wq,
                                                 const float* __restrict__ wk,
                                                 const float* __restrict__ wv,
                                                 const float* __restrict__ bq,
                                                 const float* __restrict__ bk,
                                                 const float* __restrict__ bv,
                                                 const float* __restrict__ qd,
                                                 const float* __restrict__ vd,
                                                 float* __restrict__ bqf,
                                                 float* __restrict__ bkf,
                                                 float* __restrict__ bvf) {
    int row = blockIdx.x * 4 + (threadIdx.x >> 6);   // 0..1535
    int lane = threadIdx.x & 63;
    int m = row >> 9;
    int o = row & 511;
    const float* W = (m == 0) ? wq : (m == 1) ? wk : wv;
    const float* b = (m == 0) ? bq : (m == 1) ? bk : bv;
    const float* d = (m == 0) ? qd : vd;
    float* outp    = (m == 0) ? bqf : (m == 1) ? bkf : bvf;
    const float4* wr = (const float4*)(W + (size_t)o * 512) + lane * 2;
    const float4* dr = (const float4*)d + lane * 2;
    float4 a0 = wr[0], a1 = wr[1], d0 = dr[0], d1 = dr[1];
    float acc = a0.x * d0.x + a0.y * d0.y + a0.z * d0.z + a0.w * d0.w
              + a1.x * d1.x + a1.y * d1.y + a1.z * d1.z + a1.w * d1.w;
    #pragma unroll
    for (int off = 32; off > 0; off >>= 1) acc += __shfl_xor(acc, off);
    if (lane == 0) outp[o] = b[o] + acc;
}

// ---- XT = bf16(x)^T : [4096 tok][512 chan], token-major.
__global__ __launch_bounds__(256) void xt_prep(const float* __restrict__ x,
                                               ushort_t* __restrict__ XT) {
    __shared__ float Tl[64][65];
    int t = threadIdx.x;
    int tbase = blockIdx.x << 6, cbase = blockIdx.y << 6;
    int cl = t >> 2, tq = t & 3;
    #pragma unroll
    for (int i = 0; i < 4; i++) {
        float4 f = *(const float4*)&x[(size_t)(cbase + cl) * NTOK + tbase + tq * 16 + i * 4];
        Tl[cl][tq * 16 + i * 4 + 0] = f.x;
        Tl[cl][tq * 16 + i * 4 + 1] = f.y;
        Tl[cl][tq * 16 + i * 4 + 2] = f.z;
        Tl[cl][tq * 16 + i * 4 + 3] = f.w;
    }
    __syncthreads();
    #pragma unroll
    for (int i = 0; i < 2; i++) {
        int idx = 2 * t + i;
        int row = idx >> 3, c8 = idx & 7;
        float v[8];
        #pragma unroll
        for (int j = 0; j < 8; j++) v[j] = Tl[c8 * 8 + j][row];
        uint4 u;
        u.x = pack2r(v[0], v[1]);
        u.y = pack2r(v[2], v[3]);
        u.z = pack2r(v[4], v[5]);
        u.w = pack2r(v[6], v[7]);
        *(uint4*)&XT[(size_t)(tbase + row) * 512 + cbase + c8 * 8] = u;
    }
}

// ---- QKV projection. Tile 128m x 64n, K-step 32, grid (64, 12) = 768 blocks.
// A = W*aff (fp32->bf16 at staging), B = XT copy-staged.
__global__ __launch_bounds__(256) void qkv_mfma(const ushort_t* __restrict__ XT,
                                                const float* __restrict__ wq,
                                                const float* __restrict__ wk,
                                                const float* __restrict__ wv,
                                                const float* __restrict__ bqf,
                                                const float* __restrict__ bkf,
                                                const float* __restrict__ bvf,
                                                const float* __restrict__ qa,
                                                const float* __restrict__ va,
                                                ushort_t* __restrict__ QT,
                                                ushort_t* __restrict__ KT,
                                                ushort_t* __restrict__ Vb) {
    __shared__ __align__(16) ushort_t Wl[128][40];
    __shared__ __align__(16) ushort_t Bn[64][40];
    __shared__ __align__(16) ushort_t Tl[64][136];
    int t = threadIdx.x;
    int nbase = blockIdx.x << 6;
    int y = blockIdx.y;
    int buf = y >> 2;
    int obase = (y & 3) << 7;
    const float* W    = (buf == 0) ? wq : (buf == 1) ? wk : wv;
    const float* bias = (buf == 0) ? bqf : (buf == 1) ? bkf : bvf;
    const float* aff  = (buf == 0) ? qa : va;

    int w = t >> 6, lane = t & 63, q15 = lane & 15, quad = lane >> 4;
    f32x4 acc[2][4];
    #pragma unroll
    for (int i = 0; i < 2; i++)
        #pragma unroll
        for (int j = 0; j < 4; j++) acc[i][j] = (f32x4){0.f, 0.f, 0.f, 0.f};

    int ml = t & 127, kg = t >> 7;         // A staging role (16 ch each)
    int brow = t >> 2, bseg = t & 3;       // B staging role (1 uint4 each)
    for (int ck = 0; ck < 512; ck += 32) {
        __syncthreads();
        {   // A: 128 rows x 32 k, fold affine, fp32->bf16
            const float* src = W + (size_t)(obase + ml) * 512 + ck + kg * 16;
            const float* ap = aff + ck + kg * 16;
            float v[16];
            #pragma unroll
            for (int i = 0; i < 4; i++) {
                float4 f = *(const float4*)(src + i * 4);
                v[i * 4 + 0] = f.x * ap[i * 4 + 0];
                v[i * 4 + 1] = f.y * ap[i * 4 + 1];
                v[i * 4 + 2] = f.z * ap[i * 4 + 2];
                v[i * 4 + 3] = f.w * ap[i * 4 + 3];
            }
            uint4 u0, u1;
            u0.x = pack2r(v[0], v[1]);   u0.y = pack2r(v[2], v[3]);
            u0.z = pack2r(v[4], v[5]);   u0.w = pack2r(v[6], v[7]);
            u1.x = pack2r(v[8], v[9]);   u1.y = pack2r(v[10], v[11]);
            u1.z = pack2r(v[12], v[13]); u1.w = pack2r(v[14], v[15]);
            *(uint4*)&Wl[ml][kg * 16] = u0;
            *(uint4*)&Wl[ml][kg * 16 + 8] = u1;
        }
        // B: 64 token-rows x 32 chans, 1 uint4 per thread
        *(uint4*)&Bn[brow][bseg * 8] =
            *(const uint4*)&XT[(size_t)(nbase + brow) * 512 + ck + bseg * 8];
        __syncthreads();
        bf16x8 af0 = ldfrag(&Wl[w * 32 + q15][quad * 8]);
        bf16x8 af1 = ldfrag(&Wl[w * 32 + 16 + q15][quad * 8]);
        #pragma unroll
        for (int n8 = 0; n8 < 4; n8++) {
            bf16x8 bfv = ldfrag(&Bn[n8 * 16 + q15][quad * 8]);
            acc[0][n8] = __builtin_amdgcn_mfma_f32_16x16x32_bf16(af0, bfv, acc[0][n8], 0, 0, 0);
            acc[1][n8] = __builtin_amdgcn_mfma_f32_16x16x32_bf16(af1, bfv, acc[1][n8], 0, 0, 0);
        }
    }

    if (buf == 2) {   // V: f16 [chan][tok]
        #pragma unroll
        for (int mi = 0; mi < 2; mi++)
            #pragma unroll
            for (int r = 0; r < 4; r++) {
                int o = obase + w * 32 + mi * 16 + quad * 4 + r;
                float bo = bias[o];
                #pragma unroll
                for (int n8 = 0; n8 < 4; n8++)
                    Vb[(size_t)o * NTOK + nbase + n8 * 16 + q15] = f2h(acc[mi][n8][r] + bo);
            }
        return;
    }

    // Q/K: transpose via Tl (single pass — waves own disjoint m-columns)
    ushort_t* dstT = (buf == 0) ? QT : KT;
    float qs = (buf == 0) ? SCALE : 1.0f;
    __syncthreads();
    #pragma unroll
    for (int mi = 0; mi < 2; mi++)
        #pragma unroll
        for (int r = 0; r < 4; r++) {
            int mloc = w * 32 + mi * 16 + quad * 4 + r;
            float bo = bias[obase + mloc];
            #pragma unroll
            for (int n8 = 0; n8 < 4; n8++)
                Tl[n8 * 16 + q15][mloc] = f2b((acc[mi][n8][r] + bo) * qs);
        }
    __syncthreads();
    // FIX (round 15 bug): flush ALL 64 rows x 128 m-cols = 1024 uint4
    // (was 512 -> upper 64 output channels never written).
    #pragma unroll
    for (int i = 0; i < 4; i++) {
        int idx = 4 * t + i;                // 1024 uint4: 64 rows x 16 segs
        int row = idx >> 4, ch = idx & 15;
        uint4 u = *(const uint4*)&Tl[row][ch * 8];
        *(uint4*)&dstT[(size_t)(nbase + row) * 512 + obase + ch * 8] = u;
    }
}

// ---- Attention v6: 64q/block, K-tile 128 staged per barrier, processed in
// two 64-key sub-passes (Plu reused). QK bf16, __expf, P/V f16, l via ones-MFMA.
__global__ __launch_bounds__(256) void attn_v6(ushort_t* __restrict__ QT,
                                               const ushort_t* __restrict__ KT,
                                               const ushort_t* __restrict__ V) {
    __shared__ __align__(16) ushort_t Kt[128][40];    // [key][32 chans] bf16
    __shared__ __align__(16) ushort_t Vt[32][136];    // [d][128 keys] f16
    __shared__ __align__(16) unsigned Plu[4][16][36]; // per-wave [q][key-pairs] f16
    int h = blockIdx.y;
    int t = threadIdx.x;
    int w = t >> 6, lane = t & 63, q15 = lane & 15, quad = lane >> 4;
    int qbase = blockIdx.x << 6;
    int hc = h * 32;
    const ushort_t* Vh = V + (size_t)hc * NTOK;

    bf16x8 qf = ldfrag(&QT[(size_t)(qbase + w * 16 + q15) * 512 + hc + quad * 8]);

    const uint4 onesu = {0x3C003C00u, 0x3C003C00u, 0x3C003C00u, 0x3C003C00u};
    const f16x8 ones = __builtin_bit_cast(f16x8, onesu);

    f32x4 o0 = {0.f, 0.f, 0.f, 0.f};
    f32x4 o1 = {0.f, 0.f, 0.f, 0.f};
    f32x4 lacc = {0.f, 0.f, 0.f, 0.f};

    for (int j0 = 0; j0 < NTOK; j0 += 128) {
        __syncthreads();
        #pragma unroll
        for (int i = 0; i < 2; i++) {      // K: 512 uint4 (128 rows x 4 segs)
            int idx = t + (i << 8);
            int krow = idx >> 2, kseg = idx & 3;
            *(uint4*)&Kt[krow][kseg * 8] =
                *(const uint4*)&KT[(size_t)(j0 + krow) * 512 + hc + kseg * 8];
        }
        #pragma unroll
        for (int i = 0; i < 2; i++) {      // V: 512 uint4 (32 rows x 16 segs)
            int idx = t + (i << 8);
            int vrow = idx >> 4, vseg = idx & 15;
            *(uint4*)&Vt[vrow][vseg * 8] =
                *(const uint4*)&Vh[(size_t)vrow * NTOK + j0 + vseg * 8];
        }
        __syncthreads();

        #pragma unroll
        for (int h2 = 0; h2 < 2; h2++) {   // two 64-key sub-passes
            f32x4 st[4];
            #pragma unroll
            for (int kt = 0; kt < 4; kt++) {
                bf16x8 kf = ldfrag(&Kt[h2 * 64 + kt * 16 + q15][quad * 8]);
                f32x4 z = {0.f, 0.f, 0.f, 0.f};
                st[kt] = __builtin_amdgcn_mfma_f32_16x16x32_bf16(kf, qf, z, 0, 0, 0);
            }

            #pragma unroll
            for (int kt = 0; kt < 4; kt++)
                #pragma unroll
                for (int r = 0; r < 4; r++)
                    st[kt][r] = __expf(st[kt][r]);

            asm volatile("" ::: "memory");
            #pragma unroll
            for (int kt = 0; kt < 4; kt++) {
                uint2 pp;
                pp.x = packh2(st[kt][0], st[kt][1]);
                pp.y = packh2(st[kt][2], st[kt][3]);
                *(uint2*)&Plu[w][q15][kt * 8 + quad * 2] = pp;
            }
            asm volatile("" ::: "memory");

            #pragma unroll
            for (int kc = 0; kc < 2; kc++) {
                uint4 pu = *(const uint4*)&Plu[w][q15][kc * 16 + quad * 4];
                f16x8 pf = __builtin_bit_cast(f16x8, pu);
                f16x8 v0 = ldfragh(&Vt[q15][h2 * 64 + kc * 32 + quad * 8]);
                f16x8 v1 = ldfragh(&Vt[16 + q15][h2 * 64 + kc * 32 + quad * 8]);
                o0 = __builtin_amdgcn_mfma_f32_16x16x32_f16(pf, v0, o0, 0, 0, 0);
                o1 = __builtin_amdgcn_mfma_f32_16x16x32_f16(pf, v1, o1, 0, 0, 0);
                lacc = __builtin_amdgcn_mfma_f32_16x16x32_f16(pf, ones, lacc, 0, 0, 0);
            }
        }
    }

    #pragma unroll
    for (int r = 0; r < 4; r++) {
        float li = 1.f / lacc[r];
        int q = quad * 4 + r;
        QT[(size_t)(qbase + w * 16 + q) * 512 + hc + q15]      = f2b(o0[r] * li);
        QT[(size_t)(qbase + w * 16 + q) * 512 + hc + 16 + q15] = f2b(o1[r] * li);
    }
}

// ---- Output projection: tile 64m x 64n, grid (64, 8) = 512 blocks.
__global__ __launch_bounds__(256) void oproj_mfma(const ushort_t* __restrict__ OT,
                                                  const float* __restrict__ wo,
                                                  const float* __restrict__ bo,
                                                  const float* __restrict__ x,
                                                  float* __restrict__ out) {
    __shared__ __align__(16) ushort_t Wl[64][40];
    __shared__ __align__(16) ushort_t Bn[64][40];
    int t = threadIdx.x;
    int nbase = blockIdx.x << 6;
    int obase = blockIdx.y << 6;
    int w = t >> 6, lane = t & 63, q15 = lane & 15, quad = lane >> 4;

    f32x4 acc[4];
    #pragma unroll
    for (int i = 0; i < 4; i++) acc[i] = (f32x4){0.f, 0.f, 0.f, 0.f};

    int ml = t & 63, kg = t >> 6;          // A: 8 ch each
    int brow = t >> 2, bseg = t & 3;       // B: 1 uint4 each
    for (int ck = 0; ck < 512; ck += 32) {
        __syncthreads();
        {
            const float* src = wo + (size_t)(obase + ml) * 512 + ck + kg * 8;
            float4 f0 = *(const float4*)(src + 0);
            float4 f1 = *(const float4*)(src + 4);
            uint4 u;
            u.x = pack2r(f0.x, f0.y); u.y = pack2r(f0.z, f0.w);
            u.z = pack2r(f1.x, f1.y); u.w = pack2r(f1.z, f1.w);
            *(uint4*)&Wl[ml][kg * 8] = u;
        }
        *(uint4*)&Bn[brow][bseg * 8] =
            *(const uint4*)&OT[(size_t)(nbase + brow) * 512 + ck + bseg * 8];
        __syncthreads();
        bf16x8 af = ldfrag(&Wl[w * 16 + q15][quad * 8]);
        #pragma unroll
        for (int n8 = 0; n8 < 4; n8++) {
            bf16x8 bfv = ldfrag(&Bn[n8 * 16 + q15][quad * 8]);
            acc[n8] = __builtin_amdgcn_mfma_f32_16x16x32_bf16(af, bfv, acc[n8], 0, 0, 0);
        }
    }

    #pragma unroll
    for (int r = 0; r < 4; r++) {
        int o = obase + w * 16 + quad * 4 + r;
        float b = bo[o];
        #pragma unroll
        for (int n8 = 0; n8 < 4; n8++) {
            size_t idx = (size_t)o * NTOK + nbase + n8 * 16 + q15;
            out[idx] = (acc[n8][r] + b + x[idx]) * RSQRT2;
        }
    }
}

extern "C" void kernel_launch(void* const* d_in, const int* in_sizes, int n_in,
                              void* d_out, int out_size, void* d_ws, size_t ws_size,
                              hipStream_t stream) {
    const float* x   = (const float*)d_in[0];
    const float* gnw = (const float*)d_in[1];
    const float* gnb = (const float*)d_in[2];
    const float* wq  = (const float*)d_in[3];
    const float* bq  = (const float*)d_in[4];
    const float* wk  = (const float*)d_in[5];
    const float* bk  = (const float*)d_in[6];
    const float* wv  = (const float*)d_in[7];
    const float* bv  = (const float*)d_in[8];
    const float* wo  = (const float*)d_in[9];
    const float* bo  = (const float*)d_in[10];
    float* out = (float*)d_out;

    if (ws_size < WS_NEEDED) {
        diag_kernel<<<1, 64, 0, stream>>>(out, (float)(ws_size >> 16));
        return;
    }

    char* wsb = (char*)d_ws;
    float* qa  = (float*)(wsb + 0);
    float* qd  = (float*)(wsb + 2048);
    float* va  = (float*)(wsb + 4096);
    float* vd  = (float*)(wsb + 6144);
    float* bqf = (float*)(wsb + 8192);
    float* bkf = (float*)(wsb + 10240);
    float* bvf = (float*)(wsb + 12288);
    ushort_t* XT = (ushort_t*)(wsb + 16384);               // 4 MB bf16 [4096][512]
    ushort_t* QT = (ushort_t*)(wsb + 16384 + 4194304);     // 4 MB bf16 (becomes O)
    ushort_t* KT = (ushort_t*)d_out;                        // 4 MB bf16 [4096][512]
    ushort_t* Vb = (ushort_t*)d_out + (size_t)CHAN * NTOK;  // 4 MB f16 [512][4096]

    gn_all<<<32, 256, 0, stream>>>(x, gnw, gnb, qa, qd, va, vd);
    bias_fold<<<384, 256, 0, stream>>>(wq, wk, wv, bq, bk, bv, qd, vd, bqf, bkf, bvf);
    xt_prep<<<dim3(64, 8), 256, 0, stream>>>(x, XT);

    qkv_mfma<<<dim3(64, 12), 256, 0, stream>>>(XT, wq, wk, wv, bqf, bkf, bvf,
                                               qa, va, QT, KT, Vb);

    attn_v6<<<dim3(64, 16), 256, 0, stream>>>(QT, KT, Vb);

    oproj_mfma<<<dim3(64, 8), 256, 0, stream>>>(QT, wo, bo, x, out);
}

// Round 17
// 196.224 us; speedup vs baseline: 1.6240x; 1.1248x over previous
//
#include <hip/hip_runtime.h>

#define NTOK 4096
#define CHAN 512
#define GSIZE 65536
#define RSQRT2 0.7071067811865476f
#define SCALE 0.17677669529663687f   // 1/sqrt(32)
#define WB_OFF 32768
#define QT_OFF (WB_OFF + 2097152)
#define WS_NEEDED ((size_t)(QT_OFF + 4194304))

typedef unsigned short ushort_t;
typedef __attribute__((ext_vector_type(8))) short bf16x8;
typedef __attribute__((ext_vector_type(8))) _Float16 f16x8;
typedef __attribute__((ext_vector_type(4))) float f32x4;

__device__ __forceinline__ ushort_t f2b(float f) {
    unsigned u = __float_as_uint(f);
    unsigned r = (u + 0x7FFFu + ((u >> 16) & 1u)) >> 16;
    return (ushort_t)r;
}
__device__ __forceinline__ unsigned pack2r(float a, float b) {
    unsigned ua = __float_as_uint(a), ub = __float_as_uint(b);
    return ((ua + 0x8000u) >> 16) | ((ub + 0x8000u) & 0xFFFF0000u);
}
__device__ __forceinline__ unsigned packh2(float a, float b) {
    return __builtin_bit_cast(unsigned, __builtin_amdgcn_cvt_pkrtz(a, b));
}
__device__ __forceinline__ ushort_t f2h(float f) {
    return (ushort_t)(packh2(f, f) & 0xFFFFu);
}
__device__ __forceinline__ bf16x8 ldfrag(const ushort_t* p) {
    return __builtin_bit_cast(bf16x8, *(const uint4*)p);
}
__device__ __forceinline__ f16x8 ldfragh(const ushort_t* p) {
    return __builtin_bit_cast(f16x8, *(const uint4*)p);
}

__global__ void diag_kernel(float* out, float v) {
    if (threadIdx.x == 0 && blockIdx.x == 0) out[0] = v;
}

// ---- GN pass A: per-channel sums. One block per channel (512 blocks).
__global__ __launch_bounds__(256) void gn_sums(const float* __restrict__ x,
                                               float* __restrict__ S,
                                               float* __restrict__ SS) {
    int c = blockIdx.x, t = threadIdx.x;
    const float4* p = (const float4*)(x + (size_t)c * 4096);
    float s = 0.f, ss = 0.f;
    #pragma unroll
    for (int i = 0; i < 4; i++) {
        float4 f = p[i * 256 + t];
        s += f.x + f.y + f.z + f.w;
        ss += f.x * f.x + f.y * f.y + f.z * f.z + f.w * f.w;
    }
    #pragma unroll
    for (int off = 32; off > 0; off >>= 1) {
        s += __shfl_xor(s, off);
        ss += __shfl_xor(ss, off);
    }
    __shared__ float as[4], bs[4];
    int w = t >> 6;
    if ((t & 63) == 0) { as[w] = s; bs[w] = ss; }
    __syncthreads();
    if (t == 0) {
        S[c] = as[0] + as[1] + as[2] + as[3];
        SS[c] = bs[0] + bs[1] + bs[2] + bs[3];
    }
}

// ---- GN pass B: coefficients. 1 block x 512 threads (thread = channel).
// Group (16 consecutive channels) reductions are 16-lane shfl_xor.
__global__ __launch_bounds__(512) void gn_coef(const float* __restrict__ S,
                                               const float* __restrict__ SS,
                                               const float* __restrict__ gnw,
                                               const float* __restrict__ gnb,
                                               float* __restrict__ qa,
                                               float* __restrict__ qd,
                                               float* __restrict__ va,
                                               float* __restrict__ vd) {
    int c = threadIdx.x;
    float Sc = S[c], SSc = SS[c];
    float gs = Sc, gss = SSc;
    #pragma unroll
    for (int off = 1; off < 16; off <<= 1) {
        gs += __shfl_xor(gs, off);
        gss += __shfl_xor(gss, off);
    }
    float mu = gs * (1.f / GSIZE);
    float var = gss * (1.f / GSIZE) - mu * mu;
    float r1 = rsqrtf(var + 1e-6f);
    float wc = gnw[c], bc = gnb[c];
    float a1 = r1 * wc;
    float d1 = bc - mu * a1;
    qa[c] = a1; qd[c] = d1;
    float S2 = a1 * Sc + 4096.f * d1;
    float SS2 = a1 * a1 * SSc + 2.f * a1 * d1 * Sc + 4096.f * d1 * d1;
    float gs2 = S2, gss2 = SS2;
    #pragma unroll
    for (int off = 1; off < 16; off <<= 1) {
        gs2 += __shfl_xor(gs2, off);
        gss2 += __shfl_xor(gss2, off);
    }
    float mu2 = gs2 * (1.f / GSIZE);
    float var2 = gss2 * (1.f / GSIZE) - mu2 * mu2;
    float r2 = rsqrtf(var2 + 1e-6f);
    float a2 = r2 * wc;
    va[c] = a1 * a2;
    vd[c] = a2 * (d1 - mu2) + bc;
}

// ---- Fold GN offsets into biases: b'[o] = b[o] + sum_c W[o][c]*d[c].
__global__ __launch_bounds__(256) void bias_fold(const float* __restrict__ wq,
                                                 const float* __restrict__ wk,
                                                 const float* __restrict__ wv,
                                                 const float* __restrict__ bq,
                                                 const float* __restrict__ bk,
                                                 const float* __restrict__ bv,
                                                 const float* __restrict__ qd,
                                                 const float* __restrict__ vd,
                                                 float* __restrict__ bqf,
                                                 float* __restrict__ bkf,
                                                 float* __restrict__ bvf) {
    int row = blockIdx.x * 4 + (threadIdx.x >> 6);   // 0..1535
    int lane = threadIdx.x & 63;
    int m = row >> 9;
    int o = row & 511;
    const float* W = (m == 0) ? wq : (m == 1) ? wk : wv;
    const float* b = (m == 0) ? bq : (m == 1) ? bk : bv;
    const float* d = (m == 0) ? qd : vd;
    float* outp    = (m == 0) ? bqf : (m == 1) ? bkf : bvf;
    const float4* wr = (const float4*)(W + (size_t)o * 512) + lane * 2;
    const float4* dr = (const float4*)d + lane * 2;
    float4 a0 = wr[0], a1 = wr[1], d0 = dr[0], d1 = dr[1];
    float acc = a0.x * d0.x + a0.y * d0.y + a0.z * d0.z + a0.w * d0.w
              + a1.x * d1.x + a1.y * d1.y + a1.z * d1.z + a1.w * d1.w;
    #pragma unroll
    for (int off = 32; off > 0; off >>= 1) acc += __shfl_xor(acc, off);
    if (lane == 0) outp[o] = b[o] + acc;
}

// ---- Weight prep: fp32 -> bf16 once, GN affine folded into wq/wk/wv.
// grid (256, 4); y: 0=wq(*qa) 1=wk(*va) 2=wv(*va) 3=wo(*1).
__global__ __launch_bounds__(256) void wprep(const float* __restrict__ wq,
                                             const float* __restrict__ wk,
                                             const float* __restrict__ wv,
                                             const float* __restrict__ wo,
                                             const float* __restrict__ qa,
                                             const float* __restrict__ va,
                                             ushort_t* __restrict__ Wb) {
    int y = blockIdx.y;
    const float* src = (y == 0) ? wq : (y == 1) ? wk : (y == 2) ? wv : wo;
    int i = (blockIdx.x * 256 + threadIdx.x) * 4;    // 262144 elems per matrix
    float4 f = *(const float4*)(src + i);
    if (y < 3) {
        const float* aff = (y == 0) ? qa : va;
        float4 a = *(const float4*)(aff + (i & 511));
        f.x *= a.x; f.y *= a.y; f.z *= a.z; f.w *= a.w;
    }
    uint2 u;
    u.x = pack2r(f.x, f.y);
    u.y = pack2r(f.z, f.w);
    *(uint2*)(Wb + (size_t)y * 262144 + i) = u;
}

// ---- QKV projection. Tile 128m x 64n, K-step 32, grid (64, 12).
// A = Wb uint4 copy; B = x fp32 read directly (chan-pair pack, no affine).
__global__ __launch_bounds__(256) void qkv_mfma(const float* __restrict__ x,
                                                const ushort_t* __restrict__ Wb,
                                                const float* __restrict__ bqf,
                                                const float* __restrict__ bkf,
                                                const float* __restrict__ bvf,
                                                ushort_t* __restrict__ QT,
                                                ushort_t* __restrict__ KT,
                                                ushort_t* __restrict__ Vb) {
    __shared__ __align__(16) ushort_t Wl[128][40];
    __shared__ __align__(16) ushort_t Bn[64][40];
    __shared__ __align__(16) ushort_t Tl[64][136];
    int t = threadIdx.x;
    int nbase = blockIdx.x << 6;
    int y = blockIdx.y;
    int buf = y >> 2;
    int obase = (y & 3) << 7;
    const ushort_t* Wsrc = Wb + (size_t)buf * 262144;
    const float* bias = (buf == 0) ? bqf : (buf == 1) ? bkf : bvf;

    int w = t >> 6, lane = t & 63, q15 = lane & 15, quad = lane >> 4;
    f32x4 acc[2][4];
    #pragma unroll
    for (int i = 0; i < 2; i++)
        #pragma unroll
        for (int j = 0; j < 4; j++) acc[i][j] = (f32x4){0.f, 0.f, 0.f, 0.f};

    int cpair = t >> 4, ngroup = t & 15;   // B staging roles
    for (int ck = 0; ck < 512; ck += 32) {
        __syncthreads();
        #pragma unroll
        for (int i = 0; i < 2; i++) {      // A: 512 uint4 = 128 rows x 32 k
            int idx = 2 * t + i;
            int row = idx >> 2, seg = idx & 3;
            *(uint4*)&Wl[row][seg * 8] =
                *(const uint4*)&Wsrc[(size_t)(obase + row) * 512 + ck + seg * 8];
        }
        {   // B: 64 tok x 32 chans from x, chan-pair packed
            int c0 = ck + 2 * cpair;
            int n0 = nbase + ngroup * 4;
            float4 fa = *(const float4*)&x[(size_t)c0 * NTOK + n0];
            float4 fb = *(const float4*)&x[(size_t)(c0 + 1) * NTOK + n0];
            unsigned* brow;
            brow = (unsigned*)&Bn[ngroup * 4 + 0][0]; brow[cpair] = pack2r(fa.x, fb.x);
            brow = (unsigned*)&Bn[ngroup * 4 + 1][0]; brow[cpair] = pack2r(fa.y, fb.y);
            brow = (unsigned*)&Bn[ngroup * 4 + 2][0]; brow[cpair] = pack2r(fa.z, fb.z);
            brow = (unsigned*)&Bn[ngroup * 4 + 3][0]; brow[cpair] = pack2r(fa.w, fb.w);
        }
        __syncthreads();
        bf16x8 af0 = ldfrag(&Wl[w * 32 + q15][quad * 8]);
        bf16x8 af1 = ldfrag(&Wl[w * 32 + 16 + q15][quad * 8]);
        #pragma unroll
        for (int n8 = 0; n8 < 4; n8++) {
            bf16x8 bfv = ldfrag(&Bn[n8 * 16 + q15][quad * 8]);
            acc[0][n8] = __builtin_amdgcn_mfma_f32_16x16x32_bf16(af0, bfv, acc[0][n8], 0, 0, 0);
            acc[1][n8] = __builtin_amdgcn_mfma_f32_16x16x32_bf16(af1, bfv, acc[1][n8], 0, 0, 0);
        }
    }

    if (buf == 2) {   // V: f16 [chan][tok]
        #pragma unroll
        for (int mi = 0; mi < 2; mi++)
            #pragma unroll
            for (int r = 0; r < 4; r++) {
                int o = obase + w * 32 + mi * 16 + quad * 4 + r;
                float bo = bias[o];
                #pragma unroll
                for (int n8 = 0; n8 < 4; n8++)
                    Vb[(size_t)o * NTOK + nbase + n8 * 16 + q15] = f2h(acc[mi][n8][r] + bo);
            }
        return;
    }

    // Q/K: transpose via Tl (waves own disjoint m-columns), full 1024-uint4 flush
    ushort_t* dstT = (buf == 0) ? QT : KT;
    float qs = (buf == 0) ? SCALE : 1.0f;
    __syncthreads();
    #pragma unroll
    for (int mi = 0; mi < 2; mi++)
        #pragma unroll
        for (int r = 0; r < 4; r++) {
            int mloc = w * 32 + mi * 16 + quad * 4 + r;
            float bo = bias[obase + mloc];
            #pragma unroll
            for (int n8 = 0; n8 < 4; n8++)
                Tl[n8 * 16 + q15][mloc] = f2b((acc[mi][n8][r] + bo) * qs);
        }
    __syncthreads();
    #pragma unroll
    for (int i = 0; i < 4; i++) {
        int idx = 4 * t + i;                // 1024 uint4: 64 rows x 16 segs
        int row = idx >> 4, ch = idx & 15;
        uint4 u = *(const uint4*)&Tl[row][ch * 8];
        *(uint4*)&dstT[(size_t)(nbase + row) * 512 + obase + ch * 8] = u;
    }
}

// ---- Attention v6 (unchanged from round 16): 64q/block, K-tile 128,
// two 64-key sub-passes, QK bf16, __expf, P/V f16, l via ones-MFMA.
__global__ __launch_bounds__(256) void attn_v6(ushort_t* __restrict__ QT,
                                               const ushort_t* __restrict__ KT,
                                               const ushort_t* __restrict__ V) {
    __shared__ __align__(16) ushort_t Kt[128][40];
    __shared__ __align__(16) ushort_t Vt[32][136];
    __shared__ __align__(16) unsigned Plu[4][16][36];
    int h = blockIdx.y;
    int t = threadIdx.x;
    int w = t >> 6, lane = t & 63, q15 = lane & 15, quad = lane >> 4;
    int qbase = blockIdx.x << 6;
    int hc = h * 32;
    const ushort_t* Vh = V + (size_t)hc * NTOK;

    bf16x8 qf = ldfrag(&QT[(size_t)(qbase + w * 16 + q15) * 512 + hc + quad * 8]);

    const uint4 onesu = {0x3C003C00u, 0x3C003C00u, 0x3C003C00u, 0x3C003C00u};
    const f16x8 ones = __builtin_bit_cast(f16x8, onesu);

    f32x4 o0 = {0.f, 0.f, 0.f, 0.f};
    f32x4 o1 = {0.f, 0.f, 0.f, 0.f};
    f32x4 lacc = {0.f, 0.f, 0.f, 0.f};

    for (int j0 = 0; j0 < NTOK; j0 += 128) {
        __syncthreads();
        #pragma unroll
        for (int i = 0; i < 2; i++) {
            int idx = t + (i << 8);
            int krow = idx >> 2, kseg = idx & 3;
            *(uint4*)&Kt[krow][kseg * 8] =
                *(const uint4*)&KT[(size_t)(j0 + krow) * 512 + hc + kseg * 8];
        }
        #pragma unroll
        for (int i = 0; i < 2; i++) {
            int idx = t + (i << 8);
            int vrow = idx >> 4, vseg = idx & 15;
            *(uint4*)&Vt[vrow][vseg * 8] =
                *(const uint4*)&Vh[(size_t)vrow * NTOK + j0 + vseg * 8];
        }
        __syncthreads();

        #pragma unroll
        for (int h2 = 0; h2 < 2; h2++) {
            f32x4 st[4];
            #pragma unroll
            for (int kt = 0; kt < 4; kt++) {
                bf16x8 kf = ldfrag(&Kt[h2 * 64 + kt * 16 + q15][quad * 8]);
                f32x4 z = {0.f, 0.f, 0.f, 0.f};
                st[kt] = __builtin_amdgcn_mfma_f32_16x16x32_bf16(kf, qf, z, 0, 0, 0);
            }

            #pragma unroll
            for (int kt = 0; kt < 4; kt++)
                #pragma unroll
                for (int r = 0; r < 4; r++)
                    st[kt][r] = __expf(st[kt][r]);

            asm volatile("" ::: "memory");
            #pragma unroll
            for (int kt = 0; kt < 4; kt++) {
                uint2 pp;
                pp.x = packh2(st[kt][0], st[kt][1]);
                pp.y = packh2(st[kt][2], st[kt][3]);
                *(uint2*)&Plu[w][q15][kt * 8 + quad * 2] = pp;
            }
            asm volatile("" ::: "memory");

            #pragma unroll
            for (int kc = 0; kc < 2; kc++) {
                uint4 pu = *(const uint4*)&Plu[w][q15][kc * 16 + quad * 4];
                f16x8 pf = __builtin_bit_cast(f16x8, pu);
                f16x8 v0 = ldfragh(&Vt[q15][h2 * 64 + kc * 32 + quad * 8]);
                f16x8 v1 = ldfragh(&Vt[16 + q15][h2 * 64 + kc * 32 + quad * 8]);
                o0 = __builtin_amdgcn_mfma_f32_16x16x32_f16(pf, v0, o0, 0, 0, 0);
                o1 = __builtin_amdgcn_mfma_f32_16x16x32_f16(pf, v1, o1, 0, 0, 0);
                lacc = __builtin_amdgcn_mfma_f32_16x16x32_f16(pf, ones, lacc, 0, 0, 0);
            }
        }
    }

    #pragma unroll
    for (int r = 0; r < 4; r++) {
        float li = 1.f / lacc[r];
        int q = quad * 4 + r;
        QT[(size_t)(qbase + w * 16 + q) * 512 + hc + q15]      = f2b(o0[r] * li);
        QT[(size_t)(qbase + w * 16 + q) * 512 + hc + 16 + q15] = f2b(o1[r] * li);
    }
}

// ---- Output projection: tile 64m x 64n, grid (64, 8). A = Wb[3] copy-staged.
__global__ __launch_bounds__(256) void oproj_mfma(const ushort_t* __restrict__ OT,
                                                  const ushort_t* __restrict__ Wob,
                                                  const float* __restrict__ bo,
                                                  const float* __restrict__ x,
                                                  float* __restrict__ out) {
    __shared__ __align__(16) ushort_t Wl[64][40];
    __shared__ __align__(16) ushort_t Bn[64][40];
    int t = threadIdx.x;
    int nbase = blockIdx.x << 6;
    int obase = blockIdx.y << 6;
    int w = t >> 6, lane = t & 63, q15 = lane & 15, quad = lane >> 4;

    f32x4 acc[4];
    #pragma unroll
    for (int i = 0; i < 4; i++) acc[i] = (f32x4){0.f, 0.f, 0.f, 0.f};

    int arow = t >> 2, aseg = t & 3;       // A: 256 uint4 = 64 rows x 32 k
    int brow = t >> 2, bseg = t & 3;       // B: 256 uint4 = 64 rows x 32 k
    for (int ck = 0; ck < 512; ck += 32) {
        __syncthreads();
        *(uint4*)&Wl[arow][aseg * 8] =
            *(const uint4*)&Wob[(size_t)(obase + arow) * 512 + ck + aseg * 8];
        *(uint4*)&Bn[brow][bseg * 8] =
            *(const uint4*)&OT[(size_t)(nbase + brow) * 512 + ck + bseg * 8];
        __syncthreads();
        bf16x8 af = ldfrag(&Wl[w * 16 + q15][quad * 8]);
        #pragma unroll
        for (int n8 = 0; n8 < 4; n8++) {
            bf16x8 bfv = ldfrag(&Bn[n8 * 16 + q15][quad * 8]);
            acc[n8] = __builtin_amdgcn_mfma_f32_16x16x32_bf16(af, bfv, acc[n8], 0, 0, 0);
        }
    }

    #pragma unroll
    for (int r = 0; r < 4; r++) {
        int o = obase + w * 16 + quad * 4 + r;
        float b = bo[o];
        #pragma unroll
        for (int n8 = 0; n8 < 4; n8++) {
            size_t idx = (size_t)o * NTOK + nbase + n8 * 16 + q15;
            out[idx] = (acc[n8][r] + b + x[idx]) * RSQRT2;
        }
    }
}

extern "C" void kernel_launch(void* const* d_in, const int* in_sizes, int n_in,
                              void* d_out, int out_size, void* d_ws, size_t ws_size,
                              hipStream_t stream) {
    const float* x   = (const float*)d_in[0];
    const float* gnw = (const float*)d_in[1];
    const float* gnb = (const float*)d_in[2];
    const float* wq  = (const float*)d_in[3];
    const float* bq  = (const float*)d_in[4];
    const float* wk  = (const float*)d_in[5];
    const float* bk  = (const float*)d_in[6];
    const float* wv  = (const float*)d_in[7];
    const float* bv  = (const float*)d_in[8];
    const float* wo  = (const float*)d_in[9];
    const float* bo  = (const float*)d_in[10];
    float* out = (float*)d_out;

    if (ws_size < WS_NEEDED) {
        diag_kernel<<<1, 64, 0, stream>>>(out, (float)(ws_size >> 16));
        return;
    }

    char* wsb = (char*)d_ws;
    float* S   = (float*)(wsb + 0);
    float* SS  = (float*)(wsb + 2048);
    float* qa  = (float*)(wsb + 4096);
    float* qd  = (float*)(wsb + 6144);
    float* va  = (float*)(wsb + 8192);
    float* vd  = (float*)(wsb + 10240);
    float* bqf = (float*)(wsb + 12288);
    float* bkf = (float*)(wsb + 14336);
    float* bvf = (float*)(wsb + 16384);
    ushort_t* Wb = (ushort_t*)(wsb + WB_OFF);    // 2 MB bf16 (wq'|wk'|wv'|wo)
    ushort_t* QT = (ushort_t*)(wsb + QT_OFF);    // 4 MB bf16 [4096][512] (becomes O)
    ushort_t* KT = (ushort_t*)d_out;                        // 4 MB bf16 [4096][512]
    ushort_t* Vb = (ushort_t*)d_out + (size_t)CHAN * NTOK;  // 4 MB f16 [512][4096]

    gn_sums<<<512, 256, 0, stream>>>(x, S, SS);
    gn_coef<<<1, 512, 0, stream>>>(S, SS, gnw, gnb, qa, qd, va, vd);
    bias_fold<<<384, 256, 0, stream>>>(wq, wk, wv, bq, bk, bv, qd, vd, bqf, bkf, bvf);
    wprep<<<dim3(256, 4), 256, 0, stream>>>(wq, wk, wv, wo, qa, va, Wb);

    qkv_mfma<<<dim3(64, 12), 256, 0, stream>>>(x, Wb, bqf, bkf, bvf, QT, KT, Vb);

    attn_v6<<<dim3(64, 16), 256, 0, stream>>>(QT, KT, Vb);

    oproj_mfma<<<dim3(64, 8), 256, 0, stream>>>(QT, Wb + (size_t)3 * 262144, bo, x, out);
}